// Round 6
// baseline (953.378 us; speedup 1.0000x reference)
//
#include <hip/hip_runtime.h>
#include <math.h>

#define B_    16
#define C_    256
#define H_    64
#define W_    64
#define N_    4096
#define HEADS_ 4
#define KK_   16
#define VV_   64
#define M_    7
#define PAD_  3
#define OTOT_ 144   // 64 q + 16 k + 64 v channels
#define NG_   36    // 36 groups of 4 channels
#define EPS_  1e-5f

// bf16 helpers (round-half-up; error ~2^-9 relative, fine vs threshold)
__device__ inline unsigned packbf(float a, float b) {
  unsigned ua = __float_as_uint(a) + 0x8000u;
  unsigned ub = __float_as_uint(b) + 0x8000u;
  return (ua >> 16) | (ub & 0xffff0000u);
}
__device__ inline float bflo(unsigned u) { return __uint_as_float(u << 16); }
__device__ inline float bfhi(unsigned u) { return __uint_as_float(u & 0xffff0000u); }

// ---------------------------------------------------------------------------
// K1: fused projection GEMM. proj[b, o, n] = sum_c W[o,c] * x[b,c,n]
// ---------------------------------------------------------------------------
__global__ __launch_bounds__(256) void k_proj(const float* __restrict__ x,
    const float* __restrict__ wq, const float* __restrict__ wk,
    const float* __restrict__ wv, float* __restrict__ proj) {
  __shared__ float sw[16][256];
  const int tid = threadIdx.x;
  const int o0  = blockIdx.y * 16;
  const int b   = blockIdx.z;
  const int n0  = blockIdx.x * 1024 + tid;

  for (int r = 0; r < 16; ++r) {
    int o = o0 + r;
    const float* wrow = (o < 64) ? (wq + o * C_)
                       : ((o < 80) ? (wk + (o - 64) * C_) : (wv + (o - 80) * C_));
    sw[r][tid] = wrow[tid];
  }
  __syncthreads();

  float acc[16][4];
  #pragma unroll
  for (int r = 0; r < 16; ++r)
    #pragma unroll
    for (int p = 0; p < 4; ++p) acc[r][p] = 0.f;

  const float* xb = x + (size_t)b * C_ * N_;
  for (int c0 = 0; c0 < C_; c0 += 4) {
    float xv[4][4];
    #pragma unroll
    for (int i = 0; i < 4; ++i)
      #pragma unroll
      for (int p = 0; p < 4; ++p)
        xv[i][p] = xb[(size_t)(c0 + i) * N_ + n0 + p * 256];
    #pragma unroll
    for (int i = 0; i < 4; ++i) {
      #pragma unroll
      for (int r = 0; r < 16; ++r) {
        float w = sw[r][c0 + i];
        #pragma unroll
        for (int p = 0; p < 4; ++p) acc[r][p] += w * xv[i][p];
      }
    }
  }

  float* pb = proj + ((size_t)b * OTOT_ + o0) * N_ + n0;
  #pragma unroll
  for (int r = 0; r < 16; ++r)
    #pragma unroll
    for (int p = 0; p < 4; ++p)
      pb[(size_t)r * N_ + p * 256] = acc[r][p];
}

// ---------------------------------------------------------------------------
// K2: GroupNorm stats. One block per (b, group).
// ---------------------------------------------------------------------------
__global__ __launch_bounds__(256) void k_stats(const float* __restrict__ proj,
    float* __restrict__ meanp, float* __restrict__ rstdp) {
  const int bg = blockIdx.x;
  const int b = bg / NG_, g = bg % NG_;
  const float* p = proj + ((size_t)b * OTOT_ + g * 4) * N_;
  float s = 0.f, s2 = 0.f;
  for (int i = threadIdx.x; i < 4 * N_; i += 256) {
    float v = p[i];
    s += v; s2 += v * v;
  }
  __shared__ float rs[256], rq[256];
  rs[threadIdx.x] = s; rq[threadIdx.x] = s2;
  __syncthreads();
  for (int off = 128; off > 0; off >>= 1) {
    if (threadIdx.x < off) {
      rs[threadIdx.x] += rs[threadIdx.x + off];
      rq[threadIdx.x] += rq[threadIdx.x + off];
    }
    __syncthreads();
  }
  if (threadIdx.x == 0) {
    float m   = rs[0] * (1.f / 16384.f);
    float var = rq[0] * (1.f / 16384.f) - m * m;
    meanp[bg] = m;
    rstdp[bg] = rsqrtf(var + EPS_);
  }
}

// ---------------------------------------------------------------------------
// K3: k GroupNorm-apply + softmax over n.
// ---------------------------------------------------------------------------
__global__ __launch_bounds__(256) void k_softmax(const float* __restrict__ proj,
    const float* __restrict__ meanp, const float* __restrict__ rstdp,
    const float* __restrict__ gkg, const float* __restrict__ gkb,
    float* __restrict__ ksm) {
  const int bk = blockIdx.x;
  const int b = bk >> 4, kk = bk & 15;
  const int g = 16 + (kk >> 2);
  const float mu = meanp[b * NG_ + g], rs = rstdp[b * NG_ + g];
  const float ga = gkg[kk], be = gkb[kk];
  const float* p = proj + ((size_t)b * OTOT_ + 64 + kk) * N_;
  float* o = ksm + ((size_t)b * KK_ + kk) * N_;

  float xn[16];
  float m = -1e30f;
  #pragma unroll
  for (int i = 0; i < 16; ++i) {
    float v = (p[threadIdx.x + i * 256] - mu) * rs * ga + be;
    xn[i] = v;
    m = fmaxf(m, v);
  }
  __shared__ float red[256];
  red[threadIdx.x] = m; __syncthreads();
  for (int off = 128; off > 0; off >>= 1) {
    if (threadIdx.x < off)
      red[threadIdx.x] = fmaxf(red[threadIdx.x], red[threadIdx.x + off]);
    __syncthreads();
  }
  m = red[0];
  __syncthreads();
  float s = 0.f;
  #pragma unroll
  for (int i = 0; i < 16; ++i) { xn[i] = __expf(xn[i] - m); s += xn[i]; }
  red[threadIdx.x] = s; __syncthreads();
  for (int off = 128; off > 0; off >>= 1) {
    if (threadIdx.x < off) red[threadIdx.x] += red[threadIdx.x + off];
    __syncthreads();
  }
  float inv = 1.f / red[0];
  #pragma unroll
  for (int i = 0; i < 16; ++i) o[threadIdx.x + i * 256] = xn[i] * inv;
}

// ---------------------------------------------------------------------------
// K4: content lambda. lam[b,k,v] = sum_n ksm[b,k,n] * v_norm[b,v,n].
// ---------------------------------------------------------------------------
__global__ __launch_bounds__(256) void k_lam(const float* __restrict__ proj,
    const float* __restrict__ ksm,
    const float* __restrict__ meanp, const float* __restrict__ rstdp,
    const float* __restrict__ gvg, const float* __restrict__ gvb,
    float* __restrict__ lam) {
  const int bv = blockIdx.x;
  const int b = bv >> 6, v = bv & 63;
  const int g = 20 + (v >> 2);
  const float mu = meanp[b * NG_ + g], rs = rstdp[b * NG_ + g];
  const float ga = gvg[v], be = gvb[v];
  const float* pv = proj + ((size_t)b * OTOT_ + 80 + v) * N_;
  const float* pk = ksm + (size_t)b * KK_ * N_;

  float acc[16];
  #pragma unroll
  for (int k = 0; k < 16; ++k) acc[k] = 0.f;
  for (int n = threadIdx.x; n < N_; n += 256) {
    float vn = (pv[n] - mu) * rs * ga + be;
    #pragma unroll
    for (int k = 0; k < 16; ++k) acc[k] += pk[(size_t)k * N_ + n] * vn;
  }
  __shared__ float red[64];
  const int lane = threadIdx.x & 63, wid = threadIdx.x >> 6;
  #pragma unroll
  for (int k = 0; k < 16; ++k) {
    float s = acc[k];
    #pragma unroll
    for (int off = 32; off > 0; off >>= 1) s += __shfl_down(s, off, 64);
    if (lane == 0) red[wid * 16 + k] = s;
  }
  __syncthreads();
  if (threadIdx.x < 16) {
    float s = red[threadIdx.x] + red[16 + threadIdx.x] +
              red[32 + threadIdx.x] + red[48 + threadIdx.x];
    lam[((size_t)b * KK_ + threadIdx.x) * VV_ + v] = s;
  }
}

// ---------------------------------------------------------------------------
// K5 v4: all-4-heads megablock. 1024 threads = h(4) x vlane(4) x ty(4) x
// txg(16). Tile = 4 rows x 64 cols of one batch; v-halo staged ONCE for all
// heads (was 4x). 16 waves/block, 1 block/CU -> occupancy cap 50%.
// s_qe[4h][49][256] bf16 (98KB) + single-buffered s_v[16ch][10][72] bf16
// (23KB); race-free via barrier-bracketed restage. qn kept bf16-packed
// (32 VGPR) to stay <=128 VGPR so all 16 waves fit.
// ---------------------------------------------------------------------------
__global__ __launch_bounds__(1024) void k_final(const float* __restrict__ proj,
    const float* __restrict__ meanp, const float* __restrict__ rstdp,
    const float* __restrict__ gqg, const float* __restrict__ gqb,
    const float* __restrict__ gvg, const float* __restrict__ gvb,
    const float* __restrict__ emb, const float* __restrict__ lam,
    float* __restrict__ out) {
  const int strip = blockIdx.x;       // 16 strips of 4 rows
  const int b     = blockIdx.y;
  const int r0    = strip * 4;
  const int tid   = threadIdx.x;
  const int h     = tid >> 8;         // 0..3
  const int vlane = (tid >> 6) & 3;   // 0..3
  const int slot  = tid & 63;
  const int ty    = slot >> 4;        // 0..3
  const int txg   = slot & 15;        // 0..15
  const int x0    = txg << 2;
  const int n0    = (r0 + ty) * W_ + x0;
  const int pos4  = ty * 64 + x0;

  __shared__ unsigned short s_qe[4 * 49 * 256];  // 98 KB
  __shared__ unsigned short s_v[16 * 720];       // 22.5 KB
  __shared__ float s_lam[1024];                  // 4 KB
  __shared__ float s_mu[NG_], s_rs[NG_];
  __shared__ float s_gvw[64], s_gvb[64];

  // small shared loads
  s_lam[tid & 1023] = lam[(size_t)b * 1024 + (tid & 1023)];
  if (tid < NG_) { s_mu[tid] = meanp[b * NG_ + tid]; s_rs[tid] = rstdp[b * NG_ + tid]; }
  else if (tid >= 64 && tid < 128) { s_gvw[tid - 64] = gvg[tid - 64]; s_gvb[tid - 64] = gvb[tid - 64]; }
  __syncthreads();

  const float* pb = proj + (size_t)b * OTOT_ * N_;

  // ---- stage-slot precompute: 3 slots/thread cover 16ch x 10rows x 18xf4
  const float* sp_ptr[3];
  int sp_dst[3], sp_vh[3];
  #pragma unroll
  for (int it = 0; it < 3; ++it) {
    const int i = tid + it * 1024;
    const float* p = nullptr;
    int dst = -1, vh = 0;
    if (i < 2880) {
      vh = i / 180;
      const int rem = i - vh * 180;
      const int ry  = rem / 18;
      const int rx4 = rem - ry * 18;
      const int gy  = r0 - 3 + ry;
      dst = vh * 720 + ry * 72 + (rx4 << 2);
      if (gy >= 0 && gy < H_ && rx4 >= 1 && rx4 <= 16)
        p = pb + (size_t)(80 + vh) * N_ + gy * W_ + ((rx4 << 2) - 4);
    }
    sp_ptr[it] = p; sp_dst[it] = dst; sp_vh[it] = vh;
  }

  // ---- qn (bf16-packed persistent) + qe -> s_qe
  unsigned qnp[16][2];
  {
    float qnf[4][16];
    #pragma unroll
    for (int k = 0; k < 16; ++k) {
      const int o = h * 16 + k, g = o >> 2;
      const float mu = s_mu[g], rs = s_rs[g];
      const float ga = gqg[o], be = gqb[o];
      const float4 qv = *reinterpret_cast<const float4*>(pb + (size_t)o * N_ + n0);
      qnf[0][k] = (qv.x - mu) * rs * ga + be;
      qnf[1][k] = (qv.y - mu) * rs * ga + be;
      qnf[2][k] = (qv.z - mu) * rs * ga + be;
      qnf[3][k] = (qv.w - mu) * rs * ga + be;
      qnp[k][0] = packbf(qnf[0][k], qnf[1][k]);
      qnp[k][1] = packbf(qnf[2][k], qnf[3][k]);
    }
    // taps split across vlanes (13,13,13,10); emb reads are wave-uniform
    const int t0 = vlane * 13;
    const int t1 = (t0 + 13 < 49) ? (t0 + 13) : 49;
    for (int t = t0; t < t1; ++t) {
      float p0 = 0.f, p1 = 0.f, p2 = 0.f, p3 = 0.f;
      #pragma unroll
      for (int k = 0; k < 16; ++k) {
        const float e = emb[k * 49 + t];
        p0 += qnf[0][k] * e; p1 += qnf[1][k] * e;
        p2 += qnf[2][k] * e; p3 += qnf[3][k] * e;
      }
      uint2 pk;
      pk.x = packbf(p0, p1);
      pk.y = packbf(p2, p3);
      *reinterpret_cast<uint2*>(&s_qe[(h * 49 + t) * 256 + pos4]) = pk;
    }
  }

  // ---- stage set 0 into s_v
  #pragma unroll
  for (int it = 0; it < 3; ++it) {
    if (sp_dst[it] < 0) continue;
    float4 f = make_float4(0.f, 0.f, 0.f, 0.f);
    if (sp_ptr[it]) {
      f = *reinterpret_cast<const float4*>(sp_ptr[it]);
      const int v = sp_vh[it];
      const int g = 20 + (v >> 2);
      const float mu = s_mu[g], rs = s_rs[g], ga = s_gvw[v], be = s_gvb[v];
      f.x = (f.x - mu) * rs * ga + be;
      f.y = (f.y - mu) * rs * ga + be;
      f.z = (f.z - mu) * rs * ga + be;
      f.w = (f.w - mu) * rs * ga + be;
    }
    uint2 w;
    w.x = packbf(f.x, f.y);
    w.y = packbf(f.z, f.w);
    *reinterpret_cast<uint2*>(&s_v[sp_dst[it]]) = w;
  }
  __syncthreads();   // s_qe + s_v(set0) ready

  // ---- main loop: 4 sets of 16 v-channels
  for (int s = 0; s < 4; ++s) {
    float acc[4][4];
    // content init: acc[vj][p] = sum_k qn[p][k] * lam[k, v(vj)]
    #pragma unroll
    for (int vj = 0; vj < 4; ++vj)
      #pragma unroll
      for (int p = 0; p < 4; ++p) acc[vj][p] = 0.f;
    #pragma unroll
    for (int k = 0; k < 16; ++k) {
      const float q0 = bflo(qnp[k][0]), q1 = bfhi(qnp[k][0]);
      const float q2 = bflo(qnp[k][1]), q3 = bfhi(qnp[k][1]);
      const float* lrow = &s_lam[k * 64 + s * 16 + vlane];
      #pragma unroll
      for (int vj = 0; vj < 4; ++vj) {
        const float lv = lrow[vj * 4];
        acc[vj][0] += q0 * lv; acc[vj][1] += q1 * lv;
        acc[vj][2] += q2 * lv; acc[vj][3] += q3 * lv;
      }
    }

    // conv: 7 tap-rows
    #pragma unroll
    for (int i = 0; i < 7; ++i) {
      float qeu[7][4];
      #pragma unroll
      for (int j = 0; j < 7; ++j) {
        const uint2 pk = *reinterpret_cast<const uint2*>(
            &s_qe[(h * 49 + i * 7 + j) * 256 + pos4]);
        qeu[j][0] = bflo(pk.x); qeu[j][1] = bfhi(pk.x);
        qeu[j][2] = bflo(pk.y); qeu[j][3] = bfhi(pk.y);
      }
      #pragma unroll
      for (int vj = 0; vj < 4; ++vj) {
        const int vh = vj * 4 + vlane;
        const unsigned short* sv = &s_v[vh * 720 + (ty + i) * 72 + x0];
        const uint2 wa = *reinterpret_cast<const uint2*>(sv);
        const uint2 wb = *reinterpret_cast<const uint2*>(sv + 4);
        const uint2 wc = *reinterpret_cast<const uint2*>(sv + 8);
        float wv[12];
        wv[0] = bflo(wa.x); wv[1] = bfhi(wa.x); wv[2]  = bflo(wa.y); wv[3]  = bfhi(wa.y);
        wv[4] = bflo(wb.x); wv[5] = bfhi(wb.x); wv[6]  = bflo(wb.y); wv[7]  = bfhi(wb.y);
        wv[8] = bflo(wc.x); wv[9] = bfhi(wc.x); wv[10] = bflo(wc.y); wv[11] = bfhi(wc.y);
        #pragma unroll
        for (int j = 0; j < 7; ++j)
          #pragma unroll
          for (int p = 0; p < 4; ++p)
            acc[vj][p] += qeu[j][p] * wv[p + j + 1];
      }
    }

    // store
    #pragma unroll
    for (int vj = 0; vj < 4; ++vj) {
      const int v = s * 16 + vj * 4 + vlane;
      float4 o4 = make_float4(acc[vj][0], acc[vj][1], acc[vj][2], acc[vj][3]);
      *reinterpret_cast<float4*>(out + ((size_t)b * 256 + h * 64 + v) * N_ + n0) = o4;
    }

    // restage s_v for next set (barrier-bracketed, single buffer is safe)
    if (s < 3) {
      __syncthreads();   // everyone done reading set s
      #pragma unroll
      for (int it = 0; it < 3; ++it) {
        if (sp_dst[it] < 0) continue;
        float4 f = make_float4(0.f, 0.f, 0.f, 0.f);
        if (sp_ptr[it]) {
          f = *reinterpret_cast<const float4*>(sp_ptr[it] + (size_t)(s + 1) * 16 * N_);
          const int v = (s + 1) * 16 + sp_vh[it];
          const int g = 20 + (v >> 2);
          const float mu = s_mu[g], rs = s_rs[g], ga = s_gvw[v], be = s_gvb[v];
          f.x = (f.x - mu) * rs * ga + be;
          f.y = (f.y - mu) * rs * ga + be;
          f.z = (f.z - mu) * rs * ga + be;
          f.w = (f.w - mu) * rs * ga + be;
        }
        uint2 w;
        w.x = packbf(f.x, f.y);
        w.y = packbf(f.z, f.w);
        *reinterpret_cast<uint2*>(&s_v[sp_dst[it]]) = w;
      }
      __syncthreads();   // set s+1 visible
    }
  }
}

// ---------------------------------------------------------------------------
extern "C" void kernel_launch(void* const* d_in, const int* in_sizes, int n_in,
                              void* d_out, int out_size, void* d_ws, size_t ws_size,
                              hipStream_t stream) {
  const float* x   = (const float*)d_in[0];
  const float* wq  = (const float*)d_in[1];
  const float* gqg = (const float*)d_in[2];
  const float* gqb = (const float*)d_in[3];
  const float* wk  = (const float*)d_in[4];
  const float* gkg = (const float*)d_in[5];
  const float* gkb = (const float*)d_in[6];
  const float* wv  = (const float*)d_in[7];
  const float* gvg = (const float*)d_in[8];
  const float* gvb = (const float*)d_in[9];
  const float* emb = (const float*)d_in[10];
  float* out = (float*)d_out;
  float* ws  = (float*)d_ws;

  float* proj  = ws;                                    // B*144*N floats
  float* meanp = proj + (size_t)B_ * OTOT_ * N_;        // B*36
  float* rstdp = meanp + B_ * NG_;                      // B*36
  float* ksm   = rstdp + B_ * NG_;                      // B*16*N
  float* lam   = ksm + (size_t)B_ * KK_ * N_;           // B*16*64

  k_proj<<<dim3(4, 9, B_), 256, 0, stream>>>(x, wq, wk, wv, proj);
  k_stats<<<dim3(B_ * NG_), 256, 0, stream>>>(proj, meanp, rstdp);
  k_softmax<<<dim3(B_ * KK_), 256, 0, stream>>>(proj, meanp, rstdp, gkg, gkb, ksm);
  k_lam<<<dim3(B_ * VV_), 256, 0, stream>>>(proj, ksm, meanp, rstdp, gvg, gvb, lam);
  k_final<<<dim3(16, B_), 1024, 0, stream>>>(proj, meanp, rstdp,
      gqg, gqb, gvg, gvb, emb, lam, out);
}

// Round 8
// 472.493 us; speedup vs baseline: 2.0178x; 2.0178x over previous
//
#include <hip/hip_runtime.h>
#include <math.h>

#define B_    16
#define C_    256
#define H_    64
#define W_    64
#define N_    4096
#define HEADS_ 4
#define KK_   16
#define VV_   64
#define M_    7
#define PAD_  3
#define OTOT_ 144   // 64 q + 16 k + 64 v channels
#define NG_   36    // 36 groups of 4 channels
#define EPS_  1e-5f

// bf16 helpers (round-half-up; error ~2^-9 relative, fine vs threshold)
__device__ inline unsigned packbf(float a, float b) {
  unsigned ua = __float_as_uint(a) + 0x8000u;
  unsigned ub = __float_as_uint(b) + 0x8000u;
  return (ua >> 16) | (ub & 0xffff0000u);
}
__device__ inline float bflo(unsigned u) { return __uint_as_float(u << 16); }
__device__ inline float bfhi(unsigned u) { return __uint_as_float(u & 0xffff0000u); }

// ---------------------------------------------------------------------------
// K1 v2: projection GEMM, x read ONCE. proj[b,o,n] = sum_c W[o,c]*x[b,c,n].
// 256 threads = 4 waves; wave og owns 36 consecutive o-channels (wave-uniform
// w rows -> scalar loads), lane owns one n. Also emits per-block GroupNorm
// partial sums (sum, sumsq) so k_stats never re-reads proj.
// ---------------------------------------------------------------------------
__global__ __launch_bounds__(256) void k_proj(const float* __restrict__ x,
    const float* __restrict__ wq, const float* __restrict__ wk,
    const float* __restrict__ wv, float* __restrict__ proj,
    float* __restrict__ partials) {
  const int nt = blockIdx.x;          // 64 n-tiles of 64
  const int b  = blockIdx.y;
  const int lane = threadIdx.x & 63;
  const int og   = __builtin_amdgcn_readfirstlane(threadIdx.x >> 6);  // 0..3
  const int n0   = nt * 64;
  const float* xb = x + (size_t)b * C_ * N_ + n0 + lane;

  float acc[36];
  #pragma unroll
  for (int j = 0; j < 36; ++j) acc[j] = 0.f;

  for (int c0 = 0; c0 < C_; c0 += 8) {
    float xr[8];
    #pragma unroll
    for (int i = 0; i < 8; ++i) xr[i] = xb[(size_t)(c0 + i) * N_];
    #pragma unroll
    for (int j = 0; j < 36; ++j) {
      const int o = og * 36 + j;      // wave-uniform
      const float* wr = (o < 64) ? (wq + o * C_)
                        : ((o < 80) ? (wk + (o - 64) * C_) : (wv + (o - 80) * C_));
      const float4 wa = *reinterpret_cast<const float4*>(wr + c0);
      const float4 wb4 = *reinterpret_cast<const float4*>(wr + c0 + 4);
      acc[j] += wa.x * xr[0] + wa.y * xr[1] + wa.z * xr[2] + wa.w * xr[3]
              + wb4.x * xr[4] + wb4.y * xr[5] + wb4.z * xr[6] + wb4.w * xr[7];
    }
  }

  // store + per-wave partial sums for GroupNorm stats
  float* pb = proj + ((size_t)b * OTOT_ + og * 36) * N_ + n0 + lane;
  float* pp = partials + (((size_t)b * 64 + nt) * OTOT_ + og * 36) * 2;
  #pragma unroll
  for (int j = 0; j < 36; ++j) {
    const float v = acc[j];
    pb[(size_t)j * N_] = v;
    float s = v, q = v * v;
    #pragma unroll
    for (int off = 32; off > 0; off >>= 1) {
      s += __shfl_down(s, off, 64);
      q += __shfl_down(q, off, 64);
    }
    if (lane == 0) { pp[j * 2] = s; pp[j * 2 + 1] = q; }
  }
}

// ---------------------------------------------------------------------------
// K2 v2: GroupNorm stats from partials. One block per (b, group).
// ---------------------------------------------------------------------------
__global__ __launch_bounds__(256) void k_stats(const float* __restrict__ partials,
    float* __restrict__ meanp, float* __restrict__ rstdp) {
  const int bg = blockIdx.x;           // b*36 + g
  const int b = bg / NG_, g = bg % NG_;
  const int nt = threadIdx.x >> 2, ch = threadIdx.x & 3;   // 64 x 4
  const float* p = partials + (((size_t)b * 64 + nt) * OTOT_ + g * 4 + ch) * 2;
  float s = p[0], q = p[1];
  __shared__ float rs[256], rq[256];
  rs[threadIdx.x] = s; rq[threadIdx.x] = q;
  __syncthreads();
  for (int off = 128; off > 0; off >>= 1) {
    if (threadIdx.x < off) {
      rs[threadIdx.x] += rs[threadIdx.x + off];
      rq[threadIdx.x] += rq[threadIdx.x + off];
    }
    __syncthreads();
  }
  if (threadIdx.x == 0) {
    float m   = rs[0] * (1.f / 16384.f);
    float var = rq[0] * (1.f / 16384.f) - m * m;
    meanp[bg] = m;
    rstdp[bg] = rsqrtf(var + EPS_);
  }
}

// ---------------------------------------------------------------------------
// K3: k GroupNorm-apply + softmax over n.
// ---------------------------------------------------------------------------
__global__ __launch_bounds__(256) void k_softmax(const float* __restrict__ proj,
    const float* __restrict__ meanp, const float* __restrict__ rstdp,
    const float* __restrict__ gkg, const float* __restrict__ gkb,
    float* __restrict__ ksm) {
  const int bk = blockIdx.x;
  const int b = bk >> 4, kk = bk & 15;
  const int g = 16 + (kk >> 2);
  const float mu = meanp[b * NG_ + g], rs = rstdp[b * NG_ + g];
  const float ga = gkg[kk], be = gkb[kk];
  const float* p = proj + ((size_t)b * OTOT_ + 64 + kk) * N_;
  float* o = ksm + ((size_t)b * KK_ + kk) * N_;

  float xn[16];
  float m = -1e30f;
  #pragma unroll
  for (int i = 0; i < 16; ++i) {
    float v = (p[threadIdx.x + i * 256] - mu) * rs * ga + be;
    xn[i] = v;
    m = fmaxf(m, v);
  }
  __shared__ float red[256];
  red[threadIdx.x] = m; __syncthreads();
  for (int off = 128; off > 0; off >>= 1) {
    if (threadIdx.x < off)
      red[threadIdx.x] = fmaxf(red[threadIdx.x], red[threadIdx.x + off]);
    __syncthreads();
  }
  m = red[0];
  __syncthreads();
  float s = 0.f;
  #pragma unroll
  for (int i = 0; i < 16; ++i) { xn[i] = __expf(xn[i] - m); s += xn[i]; }
  red[threadIdx.x] = s; __syncthreads();
  for (int off = 128; off > 0; off >>= 1) {
    if (threadIdx.x < off) red[threadIdx.x] += red[threadIdx.x + off];
    __syncthreads();
  }
  float inv = 1.f / red[0];
  #pragma unroll
  for (int i = 0; i < 16; ++i) o[threadIdx.x + i * 256] = xn[i] * inv;
}

// ---------------------------------------------------------------------------
// K4: content lambda. lam[b,k,v] = sum_n ksm[b,k,n] * v_norm[b,v,n].
// ---------------------------------------------------------------------------
__global__ __launch_bounds__(256) void k_lam(const float* __restrict__ proj,
    const float* __restrict__ ksm,
    const float* __restrict__ meanp, const float* __restrict__ rstdp,
    const float* __restrict__ gvg, const float* __restrict__ gvb,
    float* __restrict__ lam) {
  const int bv = blockIdx.x;
  const int b = bv >> 6, v = bv & 63;
  const int g = 20 + (v >> 2);
  const float mu = meanp[b * NG_ + g], rs = rstdp[b * NG_ + g];
  const float ga = gvg[v], be = gvb[v];
  const float* pv = proj + ((size_t)b * OTOT_ + 80 + v) * N_;
  const float* pk = ksm + (size_t)b * KK_ * N_;

  float acc[16];
  #pragma unroll
  for (int k = 0; k < 16; ++k) acc[k] = 0.f;
  for (int n = threadIdx.x; n < N_; n += 256) {
    float vn = (pv[n] - mu) * rs * ga + be;
    #pragma unroll
    for (int k = 0; k < 16; ++k) acc[k] += pk[(size_t)k * N_ + n] * vn;
  }
  __shared__ float red[64];
  const int lane = threadIdx.x & 63, wid = threadIdx.x >> 6;
  #pragma unroll
  for (int k = 0; k < 16; ++k) {
    float s = acc[k];
    #pragma unroll
    for (int off = 32; off > 0; off >>= 1) s += __shfl_down(s, off, 64);
    if (lane == 0) red[wid * 16 + k] = s;
  }
  __syncthreads();
  if (threadIdx.x < 16) {
    float s = red[threadIdx.x] + red[16 + threadIdx.x] +
              red[32 + threadIdx.x] + red[48 + threadIdx.x];
    lam[((size_t)b * KK_ + threadIdx.x) * VV_ + v] = s;
  }
}

// ---------------------------------------------------------------------------
// K5 v5b: R5 structure (4px/thread, bf16 wide LDS, s_qe) + vsplit=2, with
// R5's PROVEN dynamic staging loop (R7's precompute had wrong stride).
// Block = (strip, head*vsplit, batch): 2048 blocks of 256 threads; each
// block does 2 sets of 16 v-channels.
// ---------------------------------------------------------------------------
__global__ __launch_bounds__(256) void k_final(const float* __restrict__ proj,
    const float* __restrict__ meanp, const float* __restrict__ rstdp,
    const float* __restrict__ gqg, const float* __restrict__ gqb,
    const float* __restrict__ gvg, const float* __restrict__ gvb,
    const float* __restrict__ emb, const float* __restrict__ lam,
    float* __restrict__ out) {
  const int strip = blockIdx.x;       // 16 strips of 4 rows
  const int h     = blockIdx.y >> 1;  // head
  const int s0    = (blockIdx.y & 1) * 2;  // first v-set (of 2)
  const int b     = blockIdx.z;
  const int r0    = strip * 4;
  const int tid   = threadIdx.x;
  const int vlane = tid >> 6;         // 0..3 (= wave id)
  const int slot  = tid & 63;
  const int ty    = slot >> 4;        // 0..3
  const int txg   = slot & 15;        // 0..15
  const int x0    = txg << 2;
  const int n0    = (r0 + ty) * W_ + x0;
  const int pos4  = ty * 64 + x0;

  __shared__ unsigned short s_qe[49 * 256];   // bf16 qe[t][pos], 24.5 KB
  __shared__ unsigned short s_v[16 * 720];    // bf16 v[ch][10][72], 22.5 KB
  __shared__ float s_lam[16 * 64];
  __shared__ float s_mu[NG_], s_rs[NG_];
  __shared__ float s_gvw[64], s_gvb[64];

  float* s_emb = reinterpret_cast<float*>(s_v);  // alias: pre-stage only

  for (int i = tid; i < 784; i += 256)  s_emb[i] = emb[i];
  for (int i = tid; i < 1024; i += 256) s_lam[i] = lam[(size_t)b * 1024 + i];
  if (tid < NG_) { s_mu[tid] = meanp[b * NG_ + tid]; s_rs[tid] = rstdp[b * NG_ + tid]; }
  if (tid < 64)  { s_gvw[tid] = gvg[tid]; s_gvb[tid] = gvb[tid]; }
  __syncthreads();

  const float* pb = proj + (size_t)b * OTOT_ * N_;

  // ---- qn: GroupNormed q, 4 pixels x 16 k (float4 loads)
  float qn[4][16];
  #pragma unroll
  for (int k = 0; k < 16; ++k) {
    const int o = h * 16 + k, g = o >> 2;
    const float mu = s_mu[g], rs = s_rs[g];
    const float ga = gqg[o], be = gqb[o];
    const float4 qv = *reinterpret_cast<const float4*>(pb + (size_t)o * N_ + n0);
    qn[0][k] = (qv.x - mu) * rs * ga + be;
    qn[1][k] = (qv.y - mu) * rs * ga + be;
    qn[2][k] = (qv.z - mu) * rs * ga + be;
    qn[3][k] = (qv.w - mu) * rs * ga + be;
  }

  // ---- qe: taps split across vlanes; bf16-pack 4 pixels -> LDS
  {
    const int t0 = vlane * 13;
    const int t1 = (t0 + 13 < 49) ? (t0 + 13) : 49;
    for (int t = t0; t < t1; ++t) {
      float p0 = 0.f, p1 = 0.f, p2 = 0.f, p3 = 0.f;
      #pragma unroll
      for (int k = 0; k < 16; ++k) {
        const float e = s_emb[k * 49 + t];
        p0 += qn[0][k] * e; p1 += qn[1][k] * e;
        p2 += qn[2][k] * e; p3 += qn[3][k] * e;
      }
      uint2 pk;
      pk.x = packbf(p0, p1);
      pk.y = packbf(p2, p3);
      *reinterpret_cast<uint2*>(&s_qe[t * 256 + pos4]) = pk;
    }
  }
  __syncthreads();   // s_qe done; s_emb alias dead

  // ---- stage set s0 into s_v (R5's proven loop, +s0*16 channel offset)
  for (int i = tid; i < 16 * 180; i += 256) {
    const int vh  = i / 180;
    const int rem = i - vh * 180;
    const int ry  = rem / 18;
    const int rx4 = rem - ry * 18;
    const int v   = s0 * 16 + vh;
    const int g   = 20 + (v >> 2);
    const int gy  = r0 - 3 + ry;
    float4 f = make_float4(0.f, 0.f, 0.f, 0.f);
    if (gy >= 0 && gy < H_ && rx4 >= 1 && rx4 <= 16) {
      const int gx0 = (rx4 << 2) - 4;
      f = *reinterpret_cast<const float4*>(pb + (size_t)(80 + v) * N_ + gy * W_ + gx0);
      const float mu = s_mu[g], rs = s_rs[g], ga = s_gvw[v], be = s_gvb[v];
      f.x = (f.x - mu) * rs * ga + be;
      f.y = (f.y - mu) * rs * ga + be;
      f.z = (f.z - mu) * rs * ga + be;
      f.w = (f.w - mu) * rs * ga + be;
    }
    uint2 w;
    w.x = packbf(f.x, f.y);
    w.y = packbf(f.z, f.w);
    *reinterpret_cast<uint2*>(&s_v[vh * 720 + ry * 72 + (rx4 << 2)]) = w;
  }
  __syncthreads();

  // ---- 2 sets of 16 v-channels
  for (int si = 0; si < 2; ++si) {
    const int s = s0 + si;
    float acc[4][4];
    #pragma unroll
    for (int vj = 0; vj < 4; ++vj) {
      const int v = s * 16 + vj * 4 + vlane;
      float a0 = 0.f, a1 = 0.f, a2 = 0.f, a3 = 0.f;
      #pragma unroll
      for (int k = 0; k < 16; ++k) {
        const float lv = s_lam[k * 64 + v];
        a0 += qn[0][k] * lv; a1 += qn[1][k] * lv;
        a2 += qn[2][k] * lv; a3 += qn[3][k] * lv;
      }
      acc[vj][0] = a0; acc[vj][1] = a1; acc[vj][2] = a2; acc[vj][3] = a3;
    }

    #pragma unroll
    for (int i = 0; i < 7; ++i) {
      float qeu[7][4];
      #pragma unroll
      for (int j = 0; j < 7; ++j) {
        const uint2 pk = *reinterpret_cast<const uint2*>(&s_qe[(i * 7 + j) * 256 + pos4]);
        qeu[j][0] = bflo(pk.x); qeu[j][1] = bfhi(pk.x);
        qeu[j][2] = bflo(pk.y); qeu[j][3] = bfhi(pk.y);
      }
      #pragma unroll
      for (int vj = 0; vj < 4; ++vj) {
        const int vh = vj * 4 + vlane;
        const unsigned short* sv = &s_v[vh * 720 + (ty + i) * 72 + x0];
        const uint2 wa = *reinterpret_cast<const uint2*>(sv);
        const uint2 wb = *reinterpret_cast<const uint2*>(sv + 4);
        const uint2 wc = *reinterpret_cast<const uint2*>(sv + 8);
        float wv[12];
        wv[0] = bflo(wa.x); wv[1] = bfhi(wa.x); wv[2]  = bflo(wa.y); wv[3]  = bfhi(wa.y);
        wv[4] = bflo(wb.x); wv[5] = bfhi(wb.x); wv[6]  = bflo(wb.y); wv[7]  = bfhi(wb.y);
        wv[8] = bflo(wc.x); wv[9] = bfhi(wc.x); wv[10] = bflo(wc.y); wv[11] = bfhi(wc.y);
        #pragma unroll
        for (int j = 0; j < 7; ++j)
          #pragma unroll
          for (int p = 0; p < 4; ++p)
            acc[vj][p] += qeu[j][p] * wv[p + j + 1];
      }
    }

    #pragma unroll
    for (int vj = 0; vj < 4; ++vj) {
      const int v = s * 16 + vj * 4 + vlane;
      float4 o4 = make_float4(acc[vj][0], acc[vj][1], acc[vj][2], acc[vj][3]);
      *reinterpret_cast<float4*>(out + ((size_t)b * 256 + h * 64 + v) * N_ + n0) = o4;
    }

    if (si == 0) {
      __syncthreads();
      // restage set s0+1 (same loop, next 16 channels)
      for (int i = tid; i < 16 * 180; i += 256) {
        const int vh  = i / 180;
        const int rem = i - vh * 180;
        const int ry  = rem / 18;
        const int rx4 = rem - ry * 18;
        const int v   = (s0 + 1) * 16 + vh;
        const int g   = 20 + (v >> 2);
        const int gy  = r0 - 3 + ry;
        float4 f = make_float4(0.f, 0.f, 0.f, 0.f);
        if (gy >= 0 && gy < H_ && rx4 >= 1 && rx4 <= 16) {
          const int gx0 = (rx4 << 2) - 4;
          f = *reinterpret_cast<const float4*>(pb + (size_t)(80 + v) * N_ + gy * W_ + gx0);
          const float mu = s_mu[g], rs = s_rs[g], ga = s_gvw[v], be = s_gvb[v];
          f.x = (f.x - mu) * rs * ga + be;
          f.y = (f.y - mu) * rs * ga + be;
          f.z = (f.z - mu) * rs * ga + be;
          f.w = (f.w - mu) * rs * ga + be;
        }
        uint2 w;
        w.x = packbf(f.x, f.y);
        w.y = packbf(f.z, f.w);
        *reinterpret_cast<uint2*>(&s_v[vh * 720 + ry * 72 + (rx4 << 2)]) = w;
      }
      __syncthreads();
    }
  }
}

// ---------------------------------------------------------------------------
extern "C" void kernel_launch(void* const* d_in, const int* in_sizes, int n_in,
                              void* d_out, int out_size, void* d_ws, size_t ws_size,
                              hipStream_t stream) {
  const float* x   = (const float*)d_in[0];
  const float* wq  = (const float*)d_in[1];
  const float* gqg = (const float*)d_in[2];
  const float* gqb = (const float*)d_in[3];
  const float* wk  = (const float*)d_in[4];
  const float* gkg = (const float*)d_in[5];
  const float* gkb = (const float*)d_in[6];
  const float* wv  = (const float*)d_in[7];
  const float* gvg = (const float*)d_in[8];
  const float* gvb = (const float*)d_in[9];
  const float* emb = (const float*)d_in[10];
  float* out = (float*)d_out;
  float* ws  = (float*)d_ws;

  float* proj     = ws;                                  // B*144*N
  float* meanp    = proj + (size_t)B_ * OTOT_ * N_;      // B*36
  float* rstdp    = meanp + B_ * NG_;                    // B*36
  float* ksm      = rstdp + B_ * NG_;                    // B*16*N
  float* lam      = ksm + (size_t)B_ * KK_ * N_;         // B*16*64
  float* partials = lam + (size_t)B_ * KK_ * VV_;        // B*64*144*2

  k_proj<<<dim3(64, B_), 256, 0, stream>>>(x, wq, wk, wv, proj, partials);
  k_stats<<<dim3(B_ * NG_), 256, 0, stream>>>(partials, meanp, rstdp);
  k_softmax<<<dim3(B_ * KK_), 256, 0, stream>>>(proj, meanp, rstdp, gkg, gkb, ksm);
  k_lam<<<dim3(B_ * VV_), 256, 0, stream>>>(proj, ksm, meanp, rstdp, gvg, gvb, lam);
  k_final<<<dim3(16, 8, B_), 256, 0, stream>>>(proj, meanp, rstdp,
      gqg, gqb, gvg, gvb, emb, lam, out);
}

// Round 9
// 316.271 us; speedup vs baseline: 3.0144x; 1.4939x over previous
//
#include <hip/hip_runtime.h>
#include <math.h>

#define B_    16
#define C_    256
#define H_    64
#define W_    64
#define N_    4096
#define HEADS_ 4
#define KK_   16
#define VV_   64
#define M_    7
#define PAD_  3
#define OTOT_ 144   // 64 q + 16 k + 64 v channels
#define NG_   36    // 36 groups of 4 channels
#define EPS_  1e-5f

// bf16 helpers (round-half-up; error ~2^-9 relative, fine vs threshold)
__device__ inline unsigned packbf(float a, float b) {
  unsigned ua = __float_as_uint(a) + 0x8000u;
  unsigned ub = __float_as_uint(b) + 0x8000u;
  return (ua >> 16) | (ub & 0xffff0000u);
}
__device__ inline float bflo(unsigned u) { return __uint_as_float(u << 16); }
__device__ inline float bfhi(unsigned u) { return __uint_as_float(u & 0xffff0000u); }

// ---------------------------------------------------------------------------
// K1 (R5 proven): projection GEMM. proj[b,o,n] = sum_c W[o,c]*x[b,c,n].
// Block: (n-tile 1024, o-tile 16, b). Weights staged in LDS (broadcast
// reads); each thread owns 4 positions. x re-reads hit L3 (64 MB < 256 MB).
// ---------------------------------------------------------------------------
__global__ __launch_bounds__(256) void k_proj(const float* __restrict__ x,
    const float* __restrict__ wq, const float* __restrict__ wk,
    const float* __restrict__ wv, float* __restrict__ proj) {
  __shared__ float sw[16][256];
  const int tid = threadIdx.x;
  const int o0  = blockIdx.y * 16;
  const int b   = blockIdx.z;
  const int n0  = blockIdx.x * 1024 + tid;

  for (int r = 0; r < 16; ++r) {
    int o = o0 + r;
    const float* wrow = (o < 64) ? (wq + o * C_)
                       : ((o < 80) ? (wk + (o - 64) * C_) : (wv + (o - 80) * C_));
    sw[r][tid] = wrow[tid];  // blockDim == C_ == 256
  }
  __syncthreads();

  float acc[16][4];
  #pragma unroll
  for (int r = 0; r < 16; ++r)
    #pragma unroll
    for (int p = 0; p < 4; ++p) acc[r][p] = 0.f;

  const float* xb = x + (size_t)b * C_ * N_;
  for (int c0 = 0; c0 < C_; c0 += 4) {
    float xv[4][4];
    #pragma unroll
    for (int i = 0; i < 4; ++i)
      #pragma unroll
      for (int p = 0; p < 4; ++p)
        xv[i][p] = xb[(size_t)(c0 + i) * N_ + n0 + p * 256];
    #pragma unroll
    for (int i = 0; i < 4; ++i) {
      #pragma unroll
      for (int r = 0; r < 16; ++r) {
        float w = sw[r][c0 + i];
        #pragma unroll
        for (int p = 0; p < 4; ++p) acc[r][p] += w * xv[i][p];
      }
    }
  }

  float* pb = proj + ((size_t)b * OTOT_ + o0) * N_ + n0;
  #pragma unroll
  for (int r = 0; r < 16; ++r)
    #pragma unroll
    for (int p = 0; p < 4; ++p)
      pb[(size_t)r * N_ + p * 256] = acc[r][p];
}

// ---------------------------------------------------------------------------
// K2 (R5 proven): GroupNorm stats. One block per (b, group).
// ---------------------------------------------------------------------------
__global__ __launch_bounds__(256) void k_stats(const float* __restrict__ proj,
    float* __restrict__ meanp, float* __restrict__ rstdp) {
  const int bg = blockIdx.x;           // b*36 + g
  const int b = bg / NG_, g = bg % NG_;
  const float* p = proj + ((size_t)b * OTOT_ + g * 4) * N_;
  float s = 0.f, s2 = 0.f;
  for (int i = threadIdx.x; i < 4 * N_; i += 256) {
    float v = p[i];
    s += v; s2 += v * v;
  }
  __shared__ float rs[256], rq[256];
  rs[threadIdx.x] = s; rq[threadIdx.x] = s2;
  __syncthreads();
  for (int off = 128; off > 0; off >>= 1) {
    if (threadIdx.x < off) {
      rs[threadIdx.x] += rs[threadIdx.x + off];
      rq[threadIdx.x] += rq[threadIdx.x + off];
    }
    __syncthreads();
  }
  if (threadIdx.x == 0) {
    float m   = rs[0] * (1.f / 16384.f);
    float var = rq[0] * (1.f / 16384.f) - m * m;
    meanp[bg] = m;
    rstdp[bg] = rsqrtf(var + EPS_);
  }
}

// ---------------------------------------------------------------------------
// K3: k GroupNorm-apply + softmax over n.
// ---------------------------------------------------------------------------
__global__ __launch_bounds__(256) void k_softmax(const float* __restrict__ proj,
    const float* __restrict__ meanp, const float* __restrict__ rstdp,
    const float* __restrict__ gkg, const float* __restrict__ gkb,
    float* __restrict__ ksm) {
  const int bk = blockIdx.x;
  const int b = bk >> 4, kk = bk & 15;
  const int g = 16 + (kk >> 2);
  const float mu = meanp[b * NG_ + g], rs = rstdp[b * NG_ + g];
  const float ga = gkg[kk], be = gkb[kk];
  const float* p = proj + ((size_t)b * OTOT_ + 64 + kk) * N_;
  float* o = ksm + ((size_t)b * KK_ + kk) * N_;

  float xn[16];
  float m = -1e30f;
  #pragma unroll
  for (int i = 0; i < 16; ++i) {
    float v = (p[threadIdx.x + i * 256] - mu) * rs * ga + be;
    xn[i] = v;
    m = fmaxf(m, v);
  }
  __shared__ float red[256];
  red[threadIdx.x] = m; __syncthreads();
  for (int off = 128; off > 0; off >>= 1) {
    if (threadIdx.x < off)
      red[threadIdx.x] = fmaxf(red[threadIdx.x], red[threadIdx.x + off]);
    __syncthreads();
  }
  m = red[0];
  __syncthreads();
  float s = 0.f;
  #pragma unroll
  for (int i = 0; i < 16; ++i) { xn[i] = __expf(xn[i] - m); s += xn[i]; }
  red[threadIdx.x] = s; __syncthreads();
  for (int off = 128; off > 0; off >>= 1) {
    if (threadIdx.x < off) red[threadIdx.x] += red[threadIdx.x + off];
    __syncthreads();
  }
  float inv = 1.f / red[0];
  #pragma unroll
  for (int i = 0; i < 16; ++i) o[threadIdx.x + i * 256] = xn[i] * inv;
}

// ---------------------------------------------------------------------------
// K4: content lambda. lam[b,k,v] = sum_n ksm[b,k,n] * v_norm[b,v,n].
// ---------------------------------------------------------------------------
__global__ __launch_bounds__(256) void k_lam(const float* __restrict__ proj,
    const float* __restrict__ ksm,
    const float* __restrict__ meanp, const float* __restrict__ rstdp,
    const float* __restrict__ gvg, const float* __restrict__ gvb,
    float* __restrict__ lam) {
  const int bv = blockIdx.x;
  const int b = bv >> 6, v = bv & 63;
  const int g = 20 + (v >> 2);
  const float mu = meanp[b * NG_ + g], rs = rstdp[b * NG_ + g];
  const float ga = gvg[v], be = gvb[v];
  const float* pv = proj + ((size_t)b * OTOT_ + 80 + v) * N_;
  const float* pk = ksm + (size_t)b * KK_ * N_;

  float acc[16];
  #pragma unroll
  for (int k = 0; k < 16; ++k) acc[k] = 0.f;
  for (int n = threadIdx.x; n < N_; n += 256) {
    float vn = (pv[n] - mu) * rs * ga + be;
    #pragma unroll
    for (int k = 0; k < 16; ++k) acc[k] += pk[(size_t)k * N_ + n] * vn;
  }
  __shared__ float red[64];
  const int lane = threadIdx.x & 63, wid = threadIdx.x >> 6;
  #pragma unroll
  for (int k = 0; k < 16; ++k) {
    float s = acc[k];
    #pragma unroll
    for (int off = 32; off > 0; off >>= 1) s += __shfl_down(s, off, 64);
    if (lane == 0) red[wid * 16 + k] = s;
  }
  __syncthreads();
  if (threadIdx.x < 16) {
    float s = red[threadIdx.x] + red[16 + threadIdx.x] +
              red[32 + threadIdx.x] + red[48 + threadIdx.x];
    lam[((size_t)b * KK_ + threadIdx.x) * VV_ + v] = s;
  }
}

// ---------------------------------------------------------------------------
// K5 v5b (R8 proven): 4px/thread, bf16 wide LDS, s_qe, vsplit=2.
// Block = (strip, head*vsplit, batch): 2048 blocks of 256 threads.
// ---------------------------------------------------------------------------
__global__ __launch_bounds__(256) void k_final(const float* __restrict__ proj,
    const float* __restrict__ meanp, const float* __restrict__ rstdp,
    const float* __restrict__ gqg, const float* __restrict__ gqb,
    const float* __restrict__ gvg, const float* __restrict__ gvb,
    const float* __restrict__ emb, const float* __restrict__ lam,
    float* __restrict__ out) {
  const int strip = blockIdx.x;       // 16 strips of 4 rows
  const int h     = blockIdx.y >> 1;  // head
  const int s0    = (blockIdx.y & 1) * 2;  // first v-set (of 2)
  const int b     = blockIdx.z;
  const int r0    = strip * 4;
  const int tid   = threadIdx.x;
  const int vlane = tid >> 6;         // 0..3 (= wave id)
  const int slot  = tid & 63;
  const int ty    = slot >> 4;        // 0..3
  const int txg   = slot & 15;        // 0..15
  const int x0    = txg << 2;
  const int n0    = (r0 + ty) * W_ + x0;
  const int pos4  = ty * 64 + x0;

  __shared__ unsigned short s_qe[49 * 256];   // bf16 qe[t][pos], 24.5 KB
  __shared__ unsigned short s_v[16 * 720];    // bf16 v[ch][10][72], 22.5 KB
  __shared__ float s_lam[16 * 64];
  __shared__ float s_mu[NG_], s_rs[NG_];
  __shared__ float s_gvw[64], s_gvb[64];

  float* s_emb = reinterpret_cast<float*>(s_v);  // alias: pre-stage only

  for (int i = tid; i < 784; i += 256)  s_emb[i] = emb[i];
  for (int i = tid; i < 1024; i += 256) s_lam[i] = lam[(size_t)b * 1024 + i];
  if (tid < NG_) { s_mu[tid] = meanp[b * NG_ + tid]; s_rs[tid] = rstdp[b * NG_ + tid]; }
  if (tid < 64)  { s_gvw[tid] = gvg[tid]; s_gvb[tid] = gvb[tid]; }
  __syncthreads();

  const float* pb = proj + (size_t)b * OTOT_ * N_;

  // ---- qn: GroupNormed q, 4 pixels x 16 k (float4 loads)
  float qn[4][16];
  #pragma unroll
  for (int k = 0; k < 16; ++k) {
    const int o = h * 16 + k, g = o >> 2;
    const float mu = s_mu[g], rs = s_rs[g];
    const float ga = gqg[o], be = gqb[o];
    const float4 qv = *reinterpret_cast<const float4*>(pb + (size_t)o * N_ + n0);
    qn[0][k] = (qv.x - mu) * rs * ga + be;
    qn[1][k] = (qv.y - mu) * rs * ga + be;
    qn[2][k] = (qv.z - mu) * rs * ga + be;
    qn[3][k] = (qv.w - mu) * rs * ga + be;
  }

  // ---- qe: taps split across vlanes; bf16-pack 4 pixels -> LDS
  {
    const int t0 = vlane * 13;
    const int t1 = (t0 + 13 < 49) ? (t0 + 13) : 49;
    for (int t = t0; t < t1; ++t) {
      float p0 = 0.f, p1 = 0.f, p2 = 0.f, p3 = 0.f;
      #pragma unroll
      for (int k = 0; k < 16; ++k) {
        const float e = s_emb[k * 49 + t];
        p0 += qn[0][k] * e; p1 += qn[1][k] * e;
        p2 += qn[2][k] * e; p3 += qn[3][k] * e;
      }
      uint2 pk;
      pk.x = packbf(p0, p1);
      pk.y = packbf(p2, p3);
      *reinterpret_cast<uint2*>(&s_qe[t * 256 + pos4]) = pk;
    }
  }
  __syncthreads();   // s_qe done; s_emb alias dead

  // ---- stage set s0 into s_v
  for (int i = tid; i < 16 * 180; i += 256) {
    const int vh  = i / 180;
    const int rem = i - vh * 180;
    const int ry  = rem / 18;
    const int rx4 = rem - ry * 18;
    const int v   = s0 * 16 + vh;
    const int g   = 20 + (v >> 2);
    const int gy  = r0 - 3 + ry;
    float4 f = make_float4(0.f, 0.f, 0.f, 0.f);
    if (gy >= 0 && gy < H_ && rx4 >= 1 && rx4 <= 16) {
      const int gx0 = (rx4 << 2) - 4;
      f = *reinterpret_cast<const float4*>(pb + (size_t)(80 + v) * N_ + gy * W_ + gx0);
      const float mu = s_mu[g], rs = s_rs[g], ga = s_gvw[v], be = s_gvb[v];
      f.x = (f.x - mu) * rs * ga + be;
      f.y = (f.y - mu) * rs * ga + be;
      f.z = (f.z - mu) * rs * ga + be;
      f.w = (f.w - mu) * rs * ga + be;
    }
    uint2 w;
    w.x = packbf(f.x, f.y);
    w.y = packbf(f.z, f.w);
    *reinterpret_cast<uint2*>(&s_v[vh * 720 + ry * 72 + (rx4 << 2)]) = w;
  }
  __syncthreads();

  // ---- 2 sets of 16 v-channels
  for (int si = 0; si < 2; ++si) {
    const int s = s0 + si;
    float acc[4][4];
    #pragma unroll
    for (int vj = 0; vj < 4; ++vj) {
      const int v = s * 16 + vj * 4 + vlane;
      float a0 = 0.f, a1 = 0.f, a2 = 0.f, a3 = 0.f;
      #pragma unroll
      for (int k = 0; k < 16; ++k) {
        const float lv = s_lam[k * 64 + v];
        a0 += qn[0][k] * lv; a1 += qn[1][k] * lv;
        a2 += qn[2][k] * lv; a3 += qn[3][k] * lv;
      }
      acc[vj][0] = a0; acc[vj][1] = a1; acc[vj][2] = a2; acc[vj][3] = a3;
    }

    #pragma unroll
    for (int i = 0; i < 7; ++i) {
      float qeu[7][4];
      #pragma unroll
      for (int j = 0; j < 7; ++j) {
        const uint2 pk = *reinterpret_cast<const uint2*>(&s_qe[(i * 7 + j) * 256 + pos4]);
        qeu[j][0] = bflo(pk.x); qeu[j][1] = bfhi(pk.x);
        qeu[j][2] = bflo(pk.y); qeu[j][3] = bfhi(pk.y);
      }
      #pragma unroll
      for (int vj = 0; vj < 4; ++vj) {
        const int vh = vj * 4 + vlane;
        const unsigned short* sv = &s_v[vh * 720 + (ty + i) * 72 + x0];
        const uint2 wa = *reinterpret_cast<const uint2*>(sv);
        const uint2 wb = *reinterpret_cast<const uint2*>(sv + 4);
        const uint2 wc = *reinterpret_cast<const uint2*>(sv + 8);
        float wv[12];
        wv[0] = bflo(wa.x); wv[1] = bfhi(wa.x); wv[2]  = bflo(wa.y); wv[3]  = bfhi(wa.y);
        wv[4] = bflo(wb.x); wv[5] = bfhi(wb.x); wv[6]  = bflo(wb.y); wv[7]  = bfhi(wb.y);
        wv[8] = bflo(wc.x); wv[9] = bfhi(wc.x); wv[10] = bflo(wc.y); wv[11] = bfhi(wc.y);
        #pragma unroll
        for (int j = 0; j < 7; ++j)
          #pragma unroll
          for (int p = 0; p < 4; ++p)
            acc[vj][p] += qeu[j][p] * wv[p + j + 1];
      }
    }

    #pragma unroll
    for (int vj = 0; vj < 4; ++vj) {
      const int v = s * 16 + vj * 4 + vlane;
      float4 o4 = make_float4(acc[vj][0], acc[vj][1], acc[vj][2], acc[vj][3]);
      *reinterpret_cast<float4*>(out + ((size_t)b * 256 + h * 64 + v) * N_ + n0) = o4;
    }

    if (si == 0) {
      __syncthreads();
      // restage set s0+1 (same loop, next 16 channels)
      for (int i = tid; i < 16 * 180; i += 256) {
        const int vh  = i / 180;
        const int rem = i - vh * 180;
        const int ry  = rem / 18;
        const int rx4 = rem - ry * 18;
        const int v   = (s0 + 1) * 16 + vh;
        const int g   = 20 + (v >> 2);
        const int gy  = r0 - 3 + ry;
        float4 f = make_float4(0.f, 0.f, 0.f, 0.f);
        if (gy >= 0 && gy < H_ && rx4 >= 1 && rx4 <= 16) {
          const int gx0 = (rx4 << 2) - 4;
          f = *reinterpret_cast<const float4*>(pb + (size_t)(80 + v) * N_ + gy * W_ + gx0);
          const float mu = s_mu[g], rs = s_rs[g], ga = s_gvw[v], be = s_gvb[v];
          f.x = (f.x - mu) * rs * ga + be;
          f.y = (f.y - mu) * rs * ga + be;
          f.z = (f.z - mu) * rs * ga + be;
          f.w = (f.w - mu) * rs * ga + be;
        }
        uint2 w;
        w.x = packbf(f.x, f.y);
        w.y = packbf(f.z, f.w);
        *reinterpret_cast<uint2*>(&s_v[vh * 720 + ry * 72 + (rx4 << 2)]) = w;
      }
      __syncthreads();
    }
  }
}

// ---------------------------------------------------------------------------
extern "C" void kernel_launch(void* const* d_in, const int* in_sizes, int n_in,
                              void* d_out, int out_size, void* d_ws, size_t ws_size,
                              hipStream_t stream) {
  const float* x   = (const float*)d_in[0];
  const float* wq  = (const float*)d_in[1];
  const float* gqg = (const float*)d_in[2];
  const float* gqb = (const float*)d_in[3];
  const float* wk  = (const float*)d_in[4];
  const float* gkg = (const float*)d_in[5];
  const float* gkb = (const float*)d_in[6];
  const float* wv  = (const float*)d_in[7];
  const float* gvg = (const float*)d_in[8];
  const float* gvb = (const float*)d_in[9];
  const float* emb = (const float*)d_in[10];
  float* out = (float*)d_out;
  float* ws  = (float*)d_ws;

  float* proj  = ws;                                    // B*144*N floats
  float* meanp = proj + (size_t)B_ * OTOT_ * N_;        // B*36
  float* rstdp = meanp + B_ * NG_;                      // B*36
  float* ksm   = rstdp + B_ * NG_;                      // B*16*N
  float* lam   = ksm + (size_t)B_ * KK_ * N_;           // B*16*64

  k_proj<<<dim3(4, 9, B_), 256, 0, stream>>>(x, wq, wk, wv, proj);
  k_stats<<<dim3(B_ * NG_), 256, 0, stream>>>(proj, meanp, rstdp);
  k_softmax<<<dim3(B_ * KK_), 256, 0, stream>>>(proj, meanp, rstdp, gkg, gkb, ksm);
  k_lam<<<dim3(B_ * VV_), 256, 0, stream>>>(proj, ksm, meanp, rstdp, gvg, gvb, lam);
  k_final<<<dim3(16, 8, B_), 256, 0, stream>>>(proj, meanp, rstdp,
      gqg, gqb, gvg, gvb, emb, lam, out);
}

// Round 10
// 241.670 us; speedup vs baseline: 3.9450x; 1.3087x over previous
//
#include <hip/hip_runtime.h>
#include <math.h>

#define B_    16
#define C_    256
#define H_    64
#define W_    64
#define N_    4096
#define HEADS_ 4
#define KK_   16
#define VV_   64
#define M_    7
#define PAD_  3
#define OTOT_ 144   // 64 q + 16 k + 64 v channels
#define NG_   36    // 36 groups of 4 channels
#define EPS_  1e-5f

// bf16 helpers (round-half-up; error ~2^-9 relative, fine vs threshold)
__device__ inline unsigned packbf(float a, float b) {
  unsigned ua = __float_as_uint(a) + 0x8000u;
  unsigned ub = __float_as_uint(b) + 0x8000u;
  return (ua >> 16) | (ub & 0xffff0000u);
}
__device__ inline float bflo(unsigned u) { return __uint_as_float(u << 16); }
__device__ inline float bfhi(unsigned u) { return __uint_as_float(u & 0xffff0000u); }

// ---------------------------------------------------------------------------
// K1 (R5 proven): projection GEMM. proj[b,o,n] = sum_c W[o,c]*x[b,c,n].
// ---------------------------------------------------------------------------
__global__ __launch_bounds__(256) void k_proj(const float* __restrict__ x,
    const float* __restrict__ wq, const float* __restrict__ wk,
    const float* __restrict__ wv, float* __restrict__ proj) {
  __shared__ float sw[16][256];
  const int tid = threadIdx.x;
  const int o0  = blockIdx.y * 16;
  const int b   = blockIdx.z;
  const int n0  = blockIdx.x * 1024 + tid;

  for (int r = 0; r < 16; ++r) {
    int o = o0 + r;
    const float* wrow = (o < 64) ? (wq + o * C_)
                       : ((o < 80) ? (wk + (o - 64) * C_) : (wv + (o - 80) * C_));
    sw[r][tid] = wrow[tid];  // blockDim == C_ == 256
  }
  __syncthreads();

  float acc[16][4];
  #pragma unroll
  for (int r = 0; r < 16; ++r)
    #pragma unroll
    for (int p = 0; p < 4; ++p) acc[r][p] = 0.f;

  const float* xb = x + (size_t)b * C_ * N_;
  for (int c0 = 0; c0 < C_; c0 += 4) {
    float xv[4][4];
    #pragma unroll
    for (int i = 0; i < 4; ++i)
      #pragma unroll
      for (int p = 0; p < 4; ++p)
        xv[i][p] = xb[(size_t)(c0 + i) * N_ + n0 + p * 256];
    #pragma unroll
    for (int i = 0; i < 4; ++i) {
      #pragma unroll
      for (int r = 0; r < 16; ++r) {
        float w = sw[r][c0 + i];
        #pragma unroll
        for (int p = 0; p < 4; ++p) acc[r][p] += w * xv[i][p];
      }
    }
  }

  float* pb = proj + ((size_t)b * OTOT_ + o0) * N_ + n0;
  #pragma unroll
  for (int r = 0; r < 16; ++r)
    #pragma unroll
    for (int p = 0; p < 4; ++p)
      pb[(size_t)r * N_ + p * 256] = acc[r][p];
}

// ---------------------------------------------------------------------------
// K2 (R5 proven): GroupNorm stats. One block per (b, group).
// ---------------------------------------------------------------------------
__global__ __launch_bounds__(256) void k_stats(const float* __restrict__ proj,
    float* __restrict__ meanp, float* __restrict__ rstdp) {
  const int bg = blockIdx.x;           // b*36 + g
  const int b = bg / NG_, g = bg % NG_;
  const float* p = proj + ((size_t)b * OTOT_ + g * 4) * N_;
  float s = 0.f, s2 = 0.f;
  for (int i = threadIdx.x; i < 4 * N_; i += 256) {
    float v = p[i];
    s += v; s2 += v * v;
  }
  __shared__ float rs[256], rq[256];
  rs[threadIdx.x] = s; rq[threadIdx.x] = s2;
  __syncthreads();
  for (int off = 128; off > 0; off >>= 1) {
    if (threadIdx.x < off) {
      rs[threadIdx.x] += rs[threadIdx.x + off];
      rq[threadIdx.x] += rq[threadIdx.x + off];
    }
    __syncthreads();
  }
  if (threadIdx.x == 0) {
    float m   = rs[0] * (1.f / 16384.f);
    float var = rq[0] * (1.f / 16384.f) - m * m;
    meanp[bg] = m;
    rstdp[bg] = rsqrtf(var + EPS_);
  }
}

// ---------------------------------------------------------------------------
// K3: k GroupNorm-apply + softmax over n.
// ---------------------------------------------------------------------------
__global__ __launch_bounds__(256) void k_softmax(const float* __restrict__ proj,
    const float* __restrict__ meanp, const float* __restrict__ rstdp,
    const float* __restrict__ gkg, const float* __restrict__ gkb,
    float* __restrict__ ksm) {
  const int bk = blockIdx.x;
  const int b = bk >> 4, kk = bk & 15;
  const int g = 16 + (kk >> 2);
  const float mu = meanp[b * NG_ + g], rs = rstdp[b * NG_ + g];
  const float ga = gkg[kk], be = gkb[kk];
  const float* p = proj + ((size_t)b * OTOT_ + 64 + kk) * N_;
  float* o = ksm + ((size_t)b * KK_ + kk) * N_;

  float xn[16];
  float m = -1e30f;
  #pragma unroll
  for (int i = 0; i < 16; ++i) {
    float v = (p[threadIdx.x + i * 256] - mu) * rs * ga + be;
    xn[i] = v;
    m = fmaxf(m, v);
  }
  __shared__ float red[256];
  red[threadIdx.x] = m; __syncthreads();
  for (int off = 128; off > 0; off >>= 1) {
    if (threadIdx.x < off)
      red[threadIdx.x] = fmaxf(red[threadIdx.x], red[threadIdx.x + off]);
    __syncthreads();
  }
  m = red[0];
  __syncthreads();
  float s = 0.f;
  #pragma unroll
  for (int i = 0; i < 16; ++i) { xn[i] = __expf(xn[i] - m); s += xn[i]; }
  red[threadIdx.x] = s; __syncthreads();
  for (int off = 128; off > 0; off >>= 1) {
    if (threadIdx.x < off) red[threadIdx.x] += red[threadIdx.x + off];
    __syncthreads();
  }
  float inv = 1.f / red[0];
  #pragma unroll
  for (int i = 0; i < 16; ++i) o[threadIdx.x + i * 256] = xn[i] * inv;
}

// ---------------------------------------------------------------------------
// K4: content lambda. lam[b,k,v] = sum_n ksm[b,k,n] * v_norm[b,v,n].
// ---------------------------------------------------------------------------
__global__ __launch_bounds__(256) void k_lam(const float* __restrict__ proj,
    const float* __restrict__ ksm,
    const float* __restrict__ meanp, const float* __restrict__ rstdp,
    const float* __restrict__ gvg, const float* __restrict__ gvb,
    float* __restrict__ lam) {
  const int bv = blockIdx.x;
  const int b = bv >> 6, v = bv & 63;
  const int g = 20 + (v >> 2);
  const float mu = meanp[b * NG_ + g], rs = rstdp[b * NG_ + g];
  const float ga = gvg[v], be = gvb[v];
  const float* pv = proj + ((size_t)b * OTOT_ + 80 + v) * N_;
  const float* pk = ksm + (size_t)b * KK_ * N_;

  float acc[16];
  #pragma unroll
  for (int k = 0; k < 16; ++k) acc[k] = 0.f;
  for (int n = threadIdx.x; n < N_; n += 256) {
    float vn = (pv[n] - mu) * rs * ga + be;
    #pragma unroll
    for (int k = 0; k < 16; ++k) acc[k] += pk[(size_t)k * N_ + n] * vn;
  }
  __shared__ float red[64];
  const int lane = threadIdx.x & 63, wid = threadIdx.x >> 6;
  #pragma unroll
  for (int k = 0; k < 16; ++k) {
    float s = acc[k];
    #pragma unroll
    for (int off = 32; off > 0; off >>= 1) s += __shfl_down(s, off, 64);
    if (lane == 0) red[wid * 16 + k] = s;
  }
  __syncthreads();
  if (threadIdx.x < 16) {
    float s = red[threadIdx.x] + red[16 + threadIdx.x] +
              red[32 + threadIdx.x] + red[48 + threadIdx.x];
    lam[((size_t)b * KK_ + threadIdx.x) * VV_ + v] = s;
  }
}

// ---------------------------------------------------------------------------
// K5 v6: one v-set per block, single main barrier, XCD-L2-swizzled.
// Grid: flat 4096 = b(16) x s(4) x strip(16) x h(4). XCD-bijective remap puts
// a contiguous 512-wgid chunk (= 2 batches' worth) on each XCD so the
// staging reads hit the 4MB per-XCD L2 (proj slice per b = 2MB).
// Block: [consts->LDS | barrier0] [qn(16 f4) + qe->s_qe + stage 16ch->s_v |
// barrier1] [content(scalar lam) + 7x7 conv + store]. LDS 47KB, 1 hot barrier.
// ---------------------------------------------------------------------------
__global__ __launch_bounds__(256) void k_final(const float* __restrict__ proj,
    const float* __restrict__ meanp, const float* __restrict__ rstdp,
    const float* __restrict__ gqg, const float* __restrict__ gqb,
    const float* __restrict__ gvg, const float* __restrict__ gvb,
    const float* __restrict__ emb, const float* __restrict__ lam,
    float* __restrict__ out) {
  // ---- XCD-bijective swizzle (nwg=4096, 8 XCDs -> chunks of 512)
  const int wgid = (blockIdx.x & 7) * 512 + (blockIdx.x >> 3);
  const int b     = wgid >> 8;          // same-b contiguous within a chunk
  const int r2    = wgid & 255;
  const int h     = r2 & 3;             // heads fastest: identical v-data
  const int strip = (r2 >> 2) & 15;
  const int s     = r2 >> 6;            // v-set 0..3

  const int r0    = strip * 4;
  const int tid   = threadIdx.x;
  const int vlane = __builtin_amdgcn_readfirstlane(tid >> 6);  // wave id 0..3
  const int slot  = tid & 63;
  const int ty    = slot >> 4;          // 0..3
  const int txg   = slot & 15;          // 0..15
  const int x0    = txg << 2;
  const int n0    = (r0 + ty) * W_ + x0;
  const int pos4  = ty * 64 + x0;

  __shared__ unsigned short s_qe[49 * 256];   // bf16 qe[t][pos], 24.5 KB
  __shared__ unsigned short s_v[16 * 720];    // bf16 v[ch][10][72], 22.5 KB
  __shared__ float s_mu[NG_], s_rs[NG_];
  __shared__ float s_gvw[64], s_gvb[64];

  // phase 0: tiny constants (vector-indexed in stage loop)
  if (tid < NG_) { s_mu[tid] = meanp[b * NG_ + tid]; s_rs[tid] = rstdp[b * NG_ + tid]; }
  else if (tid >= 64 && tid < 128) { s_gvw[tid - 64] = gvg[tid - 64]; s_gvb[tid - 64] = gvb[tid - 64]; }
  __syncthreads();

  const float* pb = proj + (size_t)b * OTOT_ * N_;

  // ---- qn: GroupNormed q, 4 pixels x 16 k (float4 loads; params scalar)
  float qn[4][16];
  #pragma unroll
  for (int k = 0; k < 16; ++k) {
    const int o = h * 16 + k, g = o >> 2;
    const float mu = s_mu[g], rs = s_rs[g];
    const float ga = gqg[o], be = gqb[o];
    const float4 qv = *reinterpret_cast<const float4*>(pb + (size_t)o * N_ + n0);
    qn[0][k] = (qv.x - mu) * rs * ga + be;
    qn[1][k] = (qv.y - mu) * rs * ga + be;
    qn[2][k] = (qv.z - mu) * rs * ga + be;
    qn[3][k] = (qv.w - mu) * rs * ga + be;
  }

  // ---- qe: taps split across vlanes (13,13,13,10); emb scalar (uniform t)
  {
    const int t0 = vlane * 13;
    const int t1 = (t0 + 13 < 49) ? (t0 + 13) : 49;
    for (int t = t0; t < t1; ++t) {
      float p0 = 0.f, p1 = 0.f, p2 = 0.f, p3 = 0.f;
      #pragma unroll
      for (int k = 0; k < 16; ++k) {
        const float e = emb[k * 49 + t];
        p0 += qn[0][k] * e; p1 += qn[1][k] * e;
        p2 += qn[2][k] * e; p3 += qn[3][k] * e;
      }
      uint2 pk;
      pk.x = packbf(p0, p1);
      pk.y = packbf(p2, p3);
      *reinterpret_cast<uint2*>(&s_qe[t * 256 + pos4]) = pk;
    }
  }

  // ---- stage this block's 16-channel v-set into s_v
  for (int i = tid; i < 16 * 180; i += 256) {
    const int vh  = i / 180;
    const int rem = i - vh * 180;
    const int ry  = rem / 18;
    const int rx4 = rem - ry * 18;
    const int v   = s * 16 + vh;
    const int g   = 20 + (v >> 2);
    const int gy  = r0 - 3 + ry;
    float4 f = make_float4(0.f, 0.f, 0.f, 0.f);
    if (gy >= 0 && gy < H_ && rx4 >= 1 && rx4 <= 16) {
      const int gx0 = (rx4 << 2) - 4;
      f = *reinterpret_cast<const float4*>(pb + (size_t)(80 + v) * N_ + gy * W_ + gx0);
      const float mu = s_mu[g], rs = s_rs[g], ga = s_gvw[v], be = s_gvb[v];
      f.x = (f.x - mu) * rs * ga + be;
      f.y = (f.y - mu) * rs * ga + be;
      f.z = (f.z - mu) * rs * ga + be;
      f.w = (f.w - mu) * rs * ga + be;
    }
    uint2 w;
    w.x = packbf(f.x, f.y);
    w.y = packbf(f.z, f.w);
    *reinterpret_cast<uint2*>(&s_v[vh * 720 + ry * 72 + (rx4 << 2)]) = w;
  }
  __syncthreads();   // the one hot barrier

  // ---- content init from scalar lam loads (v wave-uniform)
  float acc[4][4];
  #pragma unroll
  for (int vj = 0; vj < 4; ++vj) {
    const int v = __builtin_amdgcn_readfirstlane(s * 16 + vj * 4 + vlane);
    const float* lrow = lam + (size_t)b * 1024 + v;
    float a0 = 0.f, a1 = 0.f, a2 = 0.f, a3 = 0.f;
    #pragma unroll
    for (int k = 0; k < 16; ++k) {
      const float lv = lrow[k * 64];     // scalar (uniform addr)
      a0 += qn[0][k] * lv; a1 += qn[1][k] * lv;
      a2 += qn[2][k] * lv; a3 += qn[3][k] * lv;
    }
    acc[vj][0] = a0; acc[vj][1] = a1; acc[vj][2] = a2; acc[vj][3] = a3;
  }

  // ---- conv: 7 tap-rows; qe row unpacked once, reused across 4 vj
  #pragma unroll
  for (int i = 0; i < 7; ++i) {
    float qeu[7][4];
    #pragma unroll
    for (int j = 0; j < 7; ++j) {
      const uint2 pk = *reinterpret_cast<const uint2*>(&s_qe[(i * 7 + j) * 256 + pos4]);
      qeu[j][0] = bflo(pk.x); qeu[j][1] = bfhi(pk.x);
      qeu[j][2] = bflo(pk.y); qeu[j][3] = bfhi(pk.y);
    }
    #pragma unroll
    for (int vj = 0; vj < 4; ++vj) {
      const int vh = vj * 4 + vlane;
      const unsigned short* sv = &s_v[vh * 720 + (ty + i) * 72 + x0];
      const uint2 wa = *reinterpret_cast<const uint2*>(sv);
      const uint2 wb = *reinterpret_cast<const uint2*>(sv + 4);
      const uint2 wc = *reinterpret_cast<const uint2*>(sv + 8);
      float wv[12];
      wv[0] = bflo(wa.x); wv[1] = bfhi(wa.x); wv[2]  = bflo(wa.y); wv[3]  = bfhi(wa.y);
      wv[4] = bflo(wb.x); wv[5] = bfhi(wb.x); wv[6]  = bflo(wb.y); wv[7]  = bfhi(wb.y);
      wv[8] = bflo(wc.x); wv[9] = bfhi(wc.x); wv[10] = bflo(wc.y); wv[11] = bfhi(wc.y);
      #pragma unroll
      for (int j = 0; j < 7; ++j)
        #pragma unroll
        for (int p = 0; p < 4; ++p)
          acc[vj][p] += qeu[j][p] * wv[p + j + 1];
    }
  }

  // ---- store (float4, coalesced)
  #pragma unroll
  for (int vj = 0; vj < 4; ++vj) {
    const int v = s * 16 + vj * 4 + vlane;
    float4 o4 = make_float4(acc[vj][0], acc[vj][1], acc[vj][2], acc[vj][3]);
    *reinterpret_cast<float4*>(out + ((size_t)b * 256 + h * 64 + v) * N_ + n0) = o4;
  }
}

// ---------------------------------------------------------------------------
extern "C" void kernel_launch(void* const* d_in, const int* in_sizes, int n_in,
                              void* d_out, int out_size, void* d_ws, size_t ws_size,
                              hipStream_t stream) {
  const float* x   = (const float*)d_in[0];
  const float* wq  = (const float*)d_in[1];
  const float* gqg = (const float*)d_in[2];
  const float* gqb = (const float*)d_in[3];
  const float* wk  = (const float*)d_in[4];
  const float* gkg = (const float*)d_in[5];
  const float* gkb = (const float*)d_in[6];
  const float* wv  = (const float*)d_in[7];
  const float* gvg = (const float*)d_in[8];
  const float* gvb = (const float*)d_in[9];
  const float* emb = (const float*)d_in[10];
  float* out = (float*)d_out;
  float* ws  = (float*)d_ws;

  float* proj  = ws;                                    // B*144*N floats
  float* meanp = proj + (size_t)B_ * OTOT_ * N_;        // B*36
  float* rstdp = meanp + B_ * NG_;                      // B*36
  float* ksm   = rstdp + B_ * NG_;                      // B*16*N
  float* lam   = ksm + (size_t)B_ * KK_ * N_;           // B*16*64

  k_proj<<<dim3(4, 9, B_), 256, 0, stream>>>(x, wq, wk, wv, proj);
  k_stats<<<dim3(B_ * NG_), 256, 0, stream>>>(proj, meanp, rstdp);
  k_softmax<<<dim3(B_ * KK_), 256, 0, stream>>>(proj, meanp, rstdp, gkg, gkb, ksm);
  k_lam<<<dim3(B_ * VV_), 256, 0, stream>>>(proj, ksm, meanp, rstdp, gvg, gvb, lam);
  k_final<<<dim3(4096), 256, 0, stream>>>(proj, meanp, rstdp,
      gqg, gqb, gvg, gvb, emb, lam, out);
}

// Round 11
// 221.930 us; speedup vs baseline: 4.2959x; 1.0889x over previous
//
#include <hip/hip_runtime.h>
#include <math.h>

#define B_    16
#define C_    256
#define H_    64
#define W_    64
#define N_    4096
#define HEADS_ 4
#define KK_   16
#define VV_   64
#define M_    7
#define PAD_  3
#define OTOT_ 144   // 64 q + 16 k + 64 v channels
#define NG_   36    // 36 groups of 4 channels
#define EPS_  1e-5f

// bf16 helpers (round-half-up; error ~2^-9 relative, fine vs threshold)
__device__ inline unsigned packbf(float a, float b) {
  unsigned ua = __float_as_uint(a) + 0x8000u;
  unsigned ub = __float_as_uint(b) + 0x8000u;
  return (ua >> 16) | (ub & 0xffff0000u);
}
__device__ inline float bflo(unsigned u) { return __uint_as_float(u << 16); }
__device__ inline float bfhi(unsigned u) { return __uint_as_float(u & 0xffff0000u); }

// ---------------------------------------------------------------------------
// K1 (R5 proven): projection GEMM. proj[b,o,n] = sum_c W[o,c]*x[b,c,n].
// ---------------------------------------------------------------------------
__global__ __launch_bounds__(256) void k_proj(const float* __restrict__ x,
    const float* __restrict__ wq, const float* __restrict__ wk,
    const float* __restrict__ wv, float* __restrict__ proj) {
  __shared__ float sw[16][256];
  const int tid = threadIdx.x;
  const int o0  = blockIdx.y * 16;
  const int b   = blockIdx.z;
  const int n0  = blockIdx.x * 1024 + tid;

  for (int r = 0; r < 16; ++r) {
    int o = o0 + r;
    const float* wrow = (o < 64) ? (wq + o * C_)
                       : ((o < 80) ? (wk + (o - 64) * C_) : (wv + (o - 80) * C_));
    sw[r][tid] = wrow[tid];  // blockDim == C_ == 256
  }
  __syncthreads();

  float acc[16][4];
  #pragma unroll
  for (int r = 0; r < 16; ++r)
    #pragma unroll
    for (int p = 0; p < 4; ++p) acc[r][p] = 0.f;

  const float* xb = x + (size_t)b * C_ * N_;
  for (int c0 = 0; c0 < C_; c0 += 4) {
    float xv[4][4];
    #pragma unroll
    for (int i = 0; i < 4; ++i)
      #pragma unroll
      for (int p = 0; p < 4; ++p)
        xv[i][p] = xb[(size_t)(c0 + i) * N_ + n0 + p * 256];
    #pragma unroll
    for (int i = 0; i < 4; ++i) {
      #pragma unroll
      for (int r = 0; r < 16; ++r) {
        float w = sw[r][c0 + i];
        #pragma unroll
        for (int p = 0; p < 4; ++p) acc[r][p] += w * xv[i][p];
      }
    }
  }

  float* pb = proj + ((size_t)b * OTOT_ + o0) * N_ + n0;
  #pragma unroll
  for (int r = 0; r < 16; ++r)
    #pragma unroll
    for (int p = 0; p < 4; ++p)
      pb[(size_t)r * N_ + p * 256] = acc[r][p];
}

// ---------------------------------------------------------------------------
// K2 (R5 proven): GroupNorm stats.
// ---------------------------------------------------------------------------
__global__ __launch_bounds__(256) void k_stats(const float* __restrict__ proj,
    float* __restrict__ meanp, float* __restrict__ rstdp) {
  const int bg = blockIdx.x;           // b*36 + g
  const int b = bg / NG_, g = bg % NG_;
  const float* p = proj + ((size_t)b * OTOT_ + g * 4) * N_;
  float s = 0.f, s2 = 0.f;
  for (int i = threadIdx.x; i < 4 * N_; i += 256) {
    float v = p[i];
    s += v; s2 += v * v;
  }
  __shared__ float rs[256], rq[256];
  rs[threadIdx.x] = s; rq[threadIdx.x] = s2;
  __syncthreads();
  for (int off = 128; off > 0; off >>= 1) {
    if (threadIdx.x < off) {
      rs[threadIdx.x] += rs[threadIdx.x + off];
      rq[threadIdx.x] += rq[threadIdx.x + off];
    }
    __syncthreads();
  }
  if (threadIdx.x == 0) {
    float m   = rs[0] * (1.f / 16384.f);
    float var = rq[0] * (1.f / 16384.f) - m * m;
    meanp[bg] = m;
    rstdp[bg] = rsqrtf(var + EPS_);
  }
}

// ---------------------------------------------------------------------------
// K3: k GroupNorm-apply + softmax over n.
// ---------------------------------------------------------------------------
__global__ __launch_bounds__(256) void k_softmax(const float* __restrict__ proj,
    const float* __restrict__ meanp, const float* __restrict__ rstdp,
    const float* __restrict__ gkg, const float* __restrict__ gkb,
    float* __restrict__ ksm) {
  const int bk = blockIdx.x;
  const int b = bk >> 4, kk = bk & 15;
  const int g = 16 + (kk >> 2);
  const float mu = meanp[b * NG_ + g], rs = rstdp[b * NG_ + g];
  const float ga = gkg[kk], be = gkb[kk];
  const float* p = proj + ((size_t)b * OTOT_ + 64 + kk) * N_;
  float* o = ksm + ((size_t)b * KK_ + kk) * N_;

  float xn[16];
  float m = -1e30f;
  #pragma unroll
  for (int i = 0; i < 16; ++i) {
    float v = (p[threadIdx.x + i * 256] - mu) * rs * ga + be;
    xn[i] = v;
    m = fmaxf(m, v);
  }
  __shared__ float red[256];
  red[threadIdx.x] = m; __syncthreads();
  for (int off = 128; off > 0; off >>= 1) {
    if (threadIdx.x < off)
      red[threadIdx.x] = fmaxf(red[threadIdx.x], red[threadIdx.x + off]);
    __syncthreads();
  }
  m = red[0];
  __syncthreads();
  float s = 0.f;
  #pragma unroll
  for (int i = 0; i < 16; ++i) { xn[i] = __expf(xn[i] - m); s += xn[i]; }
  red[threadIdx.x] = s; __syncthreads();
  for (int off = 128; off > 0; off >>= 1) {
    if (threadIdx.x < off) red[threadIdx.x] += red[threadIdx.x + off];
    __syncthreads();
  }
  float inv = 1.f / red[0];
  #pragma unroll
  for (int i = 0; i < 16; ++i) o[threadIdx.x + i * 256] = xn[i] * inv;
}

// ---------------------------------------------------------------------------
// K4: content lambda. lam[b,k,v] = sum_n ksm[b,k,n] * v_norm[b,v,n].
// ---------------------------------------------------------------------------
__global__ __launch_bounds__(256) void k_lam(const float* __restrict__ proj,
    const float* __restrict__ ksm,
    const float* __restrict__ meanp, const float* __restrict__ rstdp,
    const float* __restrict__ gvg, const float* __restrict__ gvb,
    float* __restrict__ lam) {
  const int bv = blockIdx.x;
  const int b = bv >> 6, v = bv & 63;
  const int g = 20 + (v >> 2);
  const float mu = meanp[b * NG_ + g], rs = rstdp[b * NG_ + g];
  const float ga = gvg[v], be = gvb[v];
  const float* pv = proj + ((size_t)b * OTOT_ + 80 + v) * N_;
  const float* pk = ksm + (size_t)b * KK_ * N_;

  float acc[16];
  #pragma unroll
  for (int k = 0; k < 16; ++k) acc[k] = 0.f;
  for (int n = threadIdx.x; n < N_; n += 256) {
    float vn = (pv[n] - mu) * rs * ga + be;
    #pragma unroll
    for (int k = 0; k < 16; ++k) acc[k] += pk[(size_t)k * N_ + n] * vn;
  }
  __shared__ float red[64];
  const int lane = threadIdx.x & 63, wid = threadIdx.x >> 6;
  #pragma unroll
  for (int k = 0; k < 16; ++k) {
    float s = acc[k];
    #pragma unroll
    for (int off = 32; off > 0; off >>= 1) s += __shfl_down(s, off, 64);
    if (lane == 0) red[wid * 16 + k] = s;
  }
  __syncthreads();
  if (threadIdx.x < 16) {
    float s = red[threadIdx.x] + red[16 + threadIdx.x] +
              red[32 + threadIdx.x] + red[48 + threadIdx.x];
    lam[((size_t)b * KK_ + threadIdx.x) * VV_ + v] = s;
  }
}

// ---------------------------------------------------------------------------
// K-QE (new): compute qe[t][n] = sum_k GN(q)[h,k,n]*emb[k,t] ONCE per
// (b,h,n), store bf16 to global [b][h][49][N]. Block = (strip,h,b); each
// wave covers the full 256-px strip; the 4 waves split the 49 taps.
// ---------------------------------------------------------------------------
__global__ __launch_bounds__(256) void k_qe(const float* __restrict__ proj,
    const float* __restrict__ meanp, const float* __restrict__ rstdp,
    const float* __restrict__ gqg, const float* __restrict__ gqb,
    const float* __restrict__ emb, unsigned short* __restrict__ qeb) {
  const int strip = blockIdx.x;   // 16
  const int h     = blockIdx.y;   // 4
  const int b     = blockIdx.z;   // 16
  const int r0    = strip * 4;
  const int tid   = threadIdx.x;
  const int wid   = __builtin_amdgcn_readfirstlane(tid >> 6);  // tap-split
  const int slot  = tid & 63;
  const int ty    = slot >> 4, txg = slot & 15;
  const int x0    = txg << 2;
  const int n0    = (r0 + ty) * W_ + x0;

  const float* pb = proj + (size_t)b * OTOT_ * N_;

  float qn[4][16];
  #pragma unroll
  for (int k = 0; k < 16; ++k) {
    const int o = h * 16 + k, g = o >> 2;
    const float mu = meanp[b * NG_ + g], rs = rstdp[b * NG_ + g];
    const float ga = gqg[o], be = gqb[o];
    const float4 qv = *reinterpret_cast<const float4*>(pb + (size_t)o * N_ + n0);
    qn[0][k] = (qv.x - mu) * rs * ga + be;
    qn[1][k] = (qv.y - mu) * rs * ga + be;
    qn[2][k] = (qv.z - mu) * rs * ga + be;
    qn[3][k] = (qv.w - mu) * rs * ga + be;
  }

  unsigned short* qb = qeb + (size_t)(b * 4 + h) * 49 * N_;
  const int t0 = wid * 13;
  const int t1 = (t0 + 13 < 49) ? (t0 + 13) : 49;
  for (int t = t0; t < t1; ++t) {
    float p0 = 0.f, p1 = 0.f, p2 = 0.f, p3 = 0.f;
    #pragma unroll
    for (int k = 0; k < 16; ++k) {
      const float e = emb[k * 49 + t];   // uniform -> scalar
      p0 += qn[0][k] * e; p1 += qn[1][k] * e;
      p2 += qn[2][k] * e; p3 += qn[3][k] * e;
    }
    uint2 pk;
    pk.x = packbf(p0, p1);
    pk.y = packbf(p2, p3);
    *reinterpret_cast<uint2*>(&qb[(size_t)t * N_ + n0]) = pk;
  }
}

// ---------------------------------------------------------------------------
// K5 v7: conv+combine with qe from global. One v-set per block, XCD swizzle.
// LDS only s_v (23KB) -> 6 blocks/CU. Stage loop division-free (10 uniform
// iters). Content computed k-outer with GN on the fly (no qn array).
// ---------------------------------------------------------------------------
__global__ __launch_bounds__(256) void k_final_v7(const float* __restrict__ proj,
    const float* __restrict__ meanp, const float* __restrict__ rstdp,
    const float* __restrict__ gqg, const float* __restrict__ gqb,
    const float* __restrict__ gvg, const float* __restrict__ gvb,
    const unsigned short* __restrict__ qeb, const float* __restrict__ lam,
    float* __restrict__ out) {
  const int wgid = (blockIdx.x & 7) * 512 + (blockIdx.x >> 3);
  const int b     = wgid >> 8;
  const int r2    = wgid & 255;
  const int h     = r2 & 3;
  const int strip = (r2 >> 2) & 15;
  const int s     = r2 >> 6;

  const int r0    = strip * 4;
  const int tid   = threadIdx.x;
  const int vlane = __builtin_amdgcn_readfirstlane(tid >> 6);
  const int slot  = tid & 63;
  const int ty    = slot >> 4;
  const int txg   = slot & 15;
  const int x0    = txg << 2;
  const int n0    = (r0 + ty) * W_ + x0;

  __shared__ unsigned short s_v[16 * 720];    // bf16 v[ch][10][72], 22.5 KB
  __shared__ float s_mu[NG_], s_rs[NG_];
  __shared__ float s_gvw[64], s_gvb[64];

  // phase 0: constants + zero the 2 pad columns of s_v
  if (tid < NG_) { s_mu[tid] = meanp[b * NG_ + tid]; s_rs[tid] = rstdp[b * NG_ + tid]; }
  else if (tid >= 64 && tid < 128) { s_gvw[tid - 64] = gvg[tid - 64]; s_gvb[tid - 64] = gvb[tid - 64]; }
  for (int i = tid; i < 320; i += 256) {
    const int vh = i / 20, rem = i % 20;
    const int ry = rem >> 1, side = rem & 1;
    uint2 z; z.x = 0u; z.y = 0u;
    *reinterpret_cast<uint2*>(&s_v[vh * 720 + ry * 72 + side * 68]) = z;
  }
  __syncthreads();

  const float* pb = proj + (size_t)b * OTOT_ * N_;

  // phase 1: stage this block's 16-ch v-set (division-free, 10 iters)
  {
    const int vh  = tid >> 4;          // 0..15
    const int rx4 = (tid & 15) + 1;    // 1..16
    const int gx0 = (rx4 << 2) - 4;
    const int v   = s * 16 + vh;
    const int g   = 20 + (v >> 2);
    const float mu = s_mu[g], rs = s_rs[g], ga = s_gvw[v], be = s_gvb[v];
    const float* src = pb + (size_t)(80 + v) * N_ + gx0;
    unsigned short* dst = &s_v[vh * 720 + (rx4 << 2)];
    #pragma unroll
    for (int ry = 0; ry < 10; ++ry) {
      const int gy = r0 - 3 + ry;      // block-uniform branch
      float4 f = make_float4(0.f, 0.f, 0.f, 0.f);
      if (gy >= 0 && gy < H_) {
        f = *reinterpret_cast<const float4*>(src + (size_t)gy * W_);
        f.x = (f.x - mu) * rs * ga + be;
        f.y = (f.y - mu) * rs * ga + be;
        f.z = (f.z - mu) * rs * ga + be;
        f.w = (f.w - mu) * rs * ga + be;
      }
      uint2 w;
      w.x = packbf(f.x, f.y);
      w.y = packbf(f.z, f.w);
      *reinterpret_cast<uint2*>(dst + ry * 72) = w;
    }
  }
  __syncthreads();

  // phase 2: content (k-outer, GN on the fly) + conv (qe from global)
  float acc[4][4];
  #pragma unroll
  for (int vj = 0; vj < 4; ++vj)
    #pragma unroll
    for (int p = 0; p < 4; ++p) acc[vj][p] = 0.f;

  const float* lb = lam + (size_t)b * 1024;
  #pragma unroll
  for (int k = 0; k < 16; ++k) {
    const int o = h * 16 + k, g = o >> 2;
    const float mu = s_mu[g], rs = s_rs[g];
    const float ga = gqg[o], be = gqb[o];   // uniform -> scalar
    const float4 qv = *reinterpret_cast<const float4*>(pb + (size_t)o * N_ + n0);
    const float q0 = (qv.x - mu) * rs * ga + be;
    const float q1 = (qv.y - mu) * rs * ga + be;
    const float q2 = (qv.z - mu) * rs * ga + be;
    const float q3 = (qv.w - mu) * rs * ga + be;
    #pragma unroll
    for (int vj = 0; vj < 4; ++vj) {
      const int v = __builtin_amdgcn_readfirstlane(s * 16 + vj * 4 + vlane);
      const float lv = lb[k * 64 + v];      // uniform -> scalar
      acc[vj][0] += q0 * lv; acc[vj][1] += q1 * lv;
      acc[vj][2] += q2 * lv; acc[vj][3] += q3 * lv;
    }
  }

  const unsigned short* qb = qeb + (size_t)(b * 4 + h) * 49 * N_ + n0;
  #pragma unroll
  for (int i = 0; i < 7; ++i) {
    float qeu[7][4];
    #pragma unroll
    for (int j = 0; j < 7; ++j) {
      const uint2 pk = *reinterpret_cast<const uint2*>(&qb[(size_t)(i * 7 + j) * N_]);
      qeu[j][0] = bflo(pk.x); qeu[j][1] = bfhi(pk.x);
      qeu[j][2] = bflo(pk.y); qeu[j][3] = bfhi(pk.y);
    }
    #pragma unroll
    for (int vj = 0; vj < 4; ++vj) {
      const int vh = vj * 4 + vlane;
      const unsigned short* sv = &s_v[vh * 720 + (ty + i) * 72 + x0];
      const uint2 wa = *reinterpret_cast<const uint2*>(sv);
      const uint2 wb = *reinterpret_cast<const uint2*>(sv + 4);
      const uint2 wc = *reinterpret_cast<const uint2*>(sv + 8);
      float wv[12];
      wv[0] = bflo(wa.x); wv[1] = bfhi(wa.x); wv[2]  = bflo(wa.y); wv[3]  = bfhi(wa.y);
      wv[4] = bflo(wb.x); wv[5] = bfhi(wb.x); wv[6]  = bflo(wb.y); wv[7]  = bfhi(wb.y);
      wv[8] = bflo(wc.x); wv[9] = bfhi(wc.x); wv[10] = bflo(wc.y); wv[11] = bfhi(wc.y);
      #pragma unroll
      for (int j = 0; j < 7; ++j)
        #pragma unroll
        for (int p = 0; p < 4; ++p)
          acc[vj][p] += qeu[j][p] * wv[p + j + 1];
    }
  }

  #pragma unroll
  for (int vj = 0; vj < 4; ++vj) {
    const int v = s * 16 + vj * 4 + vlane;
    float4 o4 = make_float4(acc[vj][0], acc[vj][1], acc[vj][2], acc[vj][3]);
    *reinterpret_cast<float4*>(out + ((size_t)b * 256 + h * 64 + v) * N_ + n0) = o4;
  }
}

// ---------------------------------------------------------------------------
// K5 v6 (R10 proven): fallback when workspace too small for qeb.
// ---------------------------------------------------------------------------
__global__ __launch_bounds__(256) void k_final_v6(const float* __restrict__ proj,
    const float* __restrict__ meanp, const float* __restrict__ rstdp,
    const float* __restrict__ gqg, const float* __restrict__ gqb,
    const float* __restrict__ gvg, const float* __restrict__ gvb,
    const float* __restrict__ emb, const float* __restrict__ lam,
    float* __restrict__ out) {
  const int wgid = (blockIdx.x & 7) * 512 + (blockIdx.x >> 3);
  const int b     = wgid >> 8;
  const int r2    = wgid & 255;
  const int h     = r2 & 3;
  const int strip = (r2 >> 2) & 15;
  const int s     = r2 >> 6;

  const int r0    = strip * 4;
  const int tid   = threadIdx.x;
  const int vlane = __builtin_amdgcn_readfirstlane(tid >> 6);
  const int slot  = tid & 63;
  const int ty    = slot >> 4;
  const int txg   = slot & 15;
  const int x0    = txg << 2;
  const int n0    = (r0 + ty) * W_ + x0;
  const int pos4  = ty * 64 + x0;

  __shared__ unsigned short s_qe[49 * 256];
  __shared__ unsigned short s_v[16 * 720];
  __shared__ float s_mu[NG_], s_rs[NG_];
  __shared__ float s_gvw[64], s_gvb[64];

  if (tid < NG_) { s_mu[tid] = meanp[b * NG_ + tid]; s_rs[tid] = rstdp[b * NG_ + tid]; }
  else if (tid >= 64 && tid < 128) { s_gvw[tid - 64] = gvg[tid - 64]; s_gvb[tid - 64] = gvb[tid - 64]; }
  __syncthreads();

  const float* pb = proj + (size_t)b * OTOT_ * N_;

  float qn[4][16];
  #pragma unroll
  for (int k = 0; k < 16; ++k) {
    const int o = h * 16 + k, g = o >> 2;
    const float mu = s_mu[g], rs = s_rs[g];
    const float ga = gqg[o], be = gqb[o];
    const float4 qv = *reinterpret_cast<const float4*>(pb + (size_t)o * N_ + n0);
    qn[0][k] = (qv.x - mu) * rs * ga + be;
    qn[1][k] = (qv.y - mu) * rs * ga + be;
    qn[2][k] = (qv.z - mu) * rs * ga + be;
    qn[3][k] = (qv.w - mu) * rs * ga + be;
  }

  {
    const int t0 = vlane * 13;
    const int t1 = (t0 + 13 < 49) ? (t0 + 13) : 49;
    for (int t = t0; t < t1; ++t) {
      float p0 = 0.f, p1 = 0.f, p2 = 0.f, p3 = 0.f;
      #pragma unroll
      for (int k = 0; k < 16; ++k) {
        const float e = emb[k * 49 + t];
        p0 += qn[0][k] * e; p1 += qn[1][k] * e;
        p2 += qn[2][k] * e; p3 += qn[3][k] * e;
      }
      uint2 pk;
      pk.x = packbf(p0, p1);
      pk.y = packbf(p2, p3);
      *reinterpret_cast<uint2*>(&s_qe[t * 256 + pos4]) = pk;
    }
  }

  for (int i = tid; i < 16 * 180; i += 256) {
    const int vh  = i / 180;
    const int rem = i - vh * 180;
    const int ry  = rem / 18;
    const int rx4 = rem - ry * 18;
    const int v   = s * 16 + vh;
    const int g   = 20 + (v >> 2);
    const int gy  = r0 - 3 + ry;
    float4 f = make_float4(0.f, 0.f, 0.f, 0.f);
    if (gy >= 0 && gy < H_ && rx4 >= 1 && rx4 <= 16) {
      const int gx0 = (rx4 << 2) - 4;
      f = *reinterpret_cast<const float4*>(pb + (size_t)(80 + v) * N_ + gy * W_ + gx0);
      const float mu = s_mu[g], rs = s_rs[g], ga = s_gvw[v], be = s_gvb[v];
      f.x = (f.x - mu) * rs * ga + be;
      f.y = (f.y - mu) * rs * ga + be;
      f.z = (f.z - mu) * rs * ga + be;
      f.w = (f.w - mu) * rs * ga + be;
    }
    uint2 w;
    w.x = packbf(f.x, f.y);
    w.y = packbf(f.z, f.w);
    *reinterpret_cast<uint2*>(&s_v[vh * 720 + ry * 72 + (rx4 << 2)]) = w;
  }
  __syncthreads();

  float acc[4][4];
  #pragma unroll
  for (int vj = 0; vj < 4; ++vj) {
    const int v = __builtin_amdgcn_readfirstlane(s * 16 + vj * 4 + vlane);
    const float* lrow = lam + (size_t)b * 1024 + v;
    float a0 = 0.f, a1 = 0.f, a2 = 0.f, a3 = 0.f;
    #pragma unroll
    for (int k = 0; k < 16; ++k) {
      const float lv = lrow[k * 64];
      a0 += qn[0][k] * lv; a1 += qn[1][k] * lv;
      a2 += qn[2][k] * lv; a3 += qn[3][k] * lv;
    }
    acc[vj][0] = a0; acc[vj][1] = a1; acc[vj][2] = a2; acc[vj][3] = a3;
  }

  #pragma unroll
  for (int i = 0; i < 7; ++i) {
    float qeu[7][4];
    #pragma unroll
    for (int j = 0; j < 7; ++j) {
      const uint2 pk = *reinterpret_cast<const uint2*>(&s_qe[(i * 7 + j) * 256 + pos4]);
      qeu[j][0] = bflo(pk.x); qeu[j][1] = bfhi(pk.x);
      qeu[j][2] = bflo(pk.y); qeu[j][3] = bfhi(pk.y);
    }
    #pragma unroll
    for (int vj = 0; vj < 4; ++vj) {
      const int vh = vj * 4 + vlane;
      const unsigned short* sv = &s_v[vh * 720 + (ty + i) * 72 + x0];
      const uint2 wa = *reinterpret_cast<const uint2*>(sv);
      const uint2 wb = *reinterpret_cast<const uint2*>(sv + 4);
      const uint2 wc = *reinterpret_cast<const uint2*>(sv + 8);
      float wv[12];
      wv[0] = bflo(wa.x); wv[1] = bfhi(wa.x); wv[2]  = bflo(wa.y); wv[3]  = bfhi(wa.y);
      wv[4] = bflo(wb.x); wv[5] = bfhi(wb.x); wv[6]  = bflo(wb.y); wv[7]  = bfhi(wb.y);
      wv[8] = bflo(wc.x); wv[9] = bfhi(wc.x); wv[10] = bflo(wc.y); wv[11] = bfhi(wc.y);
      #pragma unroll
      for (int j = 0; j < 7; ++j)
        #pragma unroll
        for (int p = 0; p < 4; ++p)
          acc[vj][p] += qeu[j][p] * wv[p + j + 1];
    }
  }

  #pragma unroll
  for (int vj = 0; vj < 4; ++vj) {
    const int v = s * 16 + vj * 4 + vlane;
    float4 o4 = make_float4(acc[vj][0], acc[vj][1], acc[vj][2], acc[vj][3]);
    *reinterpret_cast<float4*>(out + ((size_t)b * 256 + h * 64 + v) * N_ + n0) = o4;
  }
}

// ---------------------------------------------------------------------------
extern "C" void kernel_launch(void* const* d_in, const int* in_sizes, int n_in,
                              void* d_out, int out_size, void* d_ws, size_t ws_size,
                              hipStream_t stream) {
  const float* x   = (const float*)d_in[0];
  const float* wq  = (const float*)d_in[1];
  const float* gqg = (const float*)d_in[2];
  const float* gqb = (const float*)d_in[3];
  const float* wk  = (const float*)d_in[4];
  const float* gkg = (const float*)d_in[5];
  const float* gkb = (const float*)d_in[6];
  const float* wv  = (const float*)d_in[7];
  const float* gvg = (const float*)d_in[8];
  const float* gvb = (const float*)d_in[9];
  const float* emb = (const float*)d_in[10];
  float* out = (float*)d_out;
  float* ws  = (float*)d_ws;

  float* proj  = ws;                                    // B*144*N floats
  float* meanp = proj + (size_t)B_ * OTOT_ * N_;        // B*36
  float* rstdp = meanp + B_ * NG_;                      // B*36
  float* ksm   = rstdp + B_ * NG_;                      // B*16*N
  float* lam   = ksm + (size_t)B_ * KK_ * N_;           // B*16*64
  unsigned short* qeb = (unsigned short*)(lam + (size_t)B_ * KK_ * VV_);

  const size_t base_bytes = (size_t)((lam + (size_t)B_ * KK_ * VV_) - ws) * 4;
  const size_t qeb_bytes  = (size_t)B_ * HEADS_ * 49 * N_ * 2;
  const bool   use_v7     = (ws_size >= base_bytes + qeb_bytes);

  k_proj<<<dim3(4, 9, B_), 256, 0, stream>>>(x, wq, wk, wv, proj);
  k_stats<<<dim3(B_ * NG_), 256, 0, stream>>>(proj, meanp, rstdp);
  k_softmax<<<dim3(B_ * KK_), 256, 0, stream>>>(proj, meanp, rstdp, gkg, gkb, ksm);
  k_lam<<<dim3(B_ * VV_), 256, 0, stream>>>(proj, ksm, meanp, rstdp, gvg, gvb, lam);
  if (use_v7) {
    k_qe<<<dim3(16, HEADS_, B_), 256, 0, stream>>>(proj, meanp, rstdp, gqg, gqb, emb, qeb);
    k_final_v7<<<dim3(4096), 256, 0, stream>>>(proj, meanp, rstdp,
        gqg, gqb, gvg, gvb, qeb, lam, out);
  } else {
    k_final_v6<<<dim3(4096), 256, 0, stream>>>(proj, meanp, rstdp,
        gqg, gqb, gvg, gvb, emb, lam, out);
  }
}

// Round 12
// 220.105 us; speedup vs baseline: 4.3315x; 1.0083x over previous
//
#include <hip/hip_runtime.h>
#include <math.h>

#define B_    16
#define C_    256
#define H_    64
#define W_    64
#define N_    4096
#define HEADS_ 4
#define KK_   16
#define VV_   64
#define M_    7
#define PAD_  3
#define OTOT_ 144   // 64 q + 16 k + 64 v channels
#define NG_   36    // 36 groups of 4 channels
#define EPS_  1e-5f

// bf16 helpers (round-half-up; error ~2^-9 relative, fine vs threshold)
__device__ inline unsigned packbf(float a, float b) {
  unsigned ua = __float_as_uint(a) + 0x8000u;
  unsigned ub = __float_as_uint(b) + 0x8000u;
  return (ua >> 16) | (ub & 0xffff0000u);
}
__device__ inline float bflo(unsigned u) { return __uint_as_float(u << 16); }
__device__ inline float bfhi(unsigned u) { return __uint_as_float(u & 0xffff0000u); }

// ---------------------------------------------------------------------------
// K1 v3: projection GEMM, o-tile 8 (grid 1152 blocks = 4.5/CU for occupancy).
// proj[b,o,n] = sum_c W[o,c]*x[b,c,n]. x re-reads hit L3.
// ---------------------------------------------------------------------------
__global__ __launch_bounds__(256) void k_proj(const float* __restrict__ x,
    const float* __restrict__ wq, const float* __restrict__ wk,
    const float* __restrict__ wv, float* __restrict__ proj) {
  __shared__ float sw[8][256];
  const int tid = threadIdx.x;
  const int o0  = blockIdx.y * 8;
  const int b   = blockIdx.z;
  const int n0  = blockIdx.x * 1024 + tid;

  #pragma unroll
  for (int r = 0; r < 8; ++r) {
    int o = o0 + r;
    const float* wrow = (o < 64) ? (wq + o * C_)
                       : ((o < 80) ? (wk + (o - 64) * C_) : (wv + (o - 80) * C_));
    sw[r][tid] = wrow[tid];  // blockDim == C_ == 256
  }
  __syncthreads();

  float acc[8][4];
  #pragma unroll
  for (int r = 0; r < 8; ++r)
    #pragma unroll
    for (int p = 0; p < 4; ++p) acc[r][p] = 0.f;

  const float* xb = x + (size_t)b * C_ * N_;
  for (int c0 = 0; c0 < C_; c0 += 4) {
    float xv[4][4];
    #pragma unroll
    for (int i = 0; i < 4; ++i)
      #pragma unroll
      for (int p = 0; p < 4; ++p)
        xv[i][p] = xb[(size_t)(c0 + i) * N_ + n0 + p * 256];
    #pragma unroll
    for (int i = 0; i < 4; ++i) {
      #pragma unroll
      for (int r = 0; r < 8; ++r) {
        float w = sw[r][c0 + i];
        #pragma unroll
        for (int p = 0; p < 4; ++p) acc[r][p] += w * xv[i][p];
      }
    }
  }

  float* pb = proj + ((size_t)b * OTOT_ + o0) * N_ + n0;
  #pragma unroll
  for (int r = 0; r < 8; ++r)
    #pragma unroll
    for (int p = 0; p < 4; ++p)
      pb[(size_t)r * N_ + p * 256] = acc[r][p];
}

// ---------------------------------------------------------------------------
// K2 v3: GroupNorm stats, float4 loads.
// ---------------------------------------------------------------------------
__global__ __launch_bounds__(256) void k_stats(const float* __restrict__ proj,
    float* __restrict__ meanp, float* __restrict__ rstdp) {
  const int bg = blockIdx.x;           // b*36 + g
  const int b = bg / NG_, g = bg % NG_;
  const float* p = proj + ((size_t)b * OTOT_ + g * 4) * N_;
  float s = 0.f, s2 = 0.f;
  for (int i = threadIdx.x * 4; i < 4 * N_; i += 1024) {
    const float4 v = *reinterpret_cast<const float4*>(p + i);
    s  += v.x + v.y + v.z + v.w;
    s2 += v.x * v.x + v.y * v.y + v.z * v.z + v.w * v.w;
  }
  __shared__ float rs[256], rq[256];
  rs[threadIdx.x] = s; rq[threadIdx.x] = s2;
  __syncthreads();
  for (int off = 128; off > 0; off >>= 1) {
    if (threadIdx.x < off) {
      rs[threadIdx.x] += rs[threadIdx.x + off];
      rq[threadIdx.x] += rq[threadIdx.x + off];
    }
    __syncthreads();
  }
  if (threadIdx.x == 0) {
    float m   = rs[0] * (1.f / 16384.f);
    float var = rq[0] * (1.f / 16384.f) - m * m;
    meanp[bg] = m;
    rstdp[bg] = rsqrtf(var + EPS_);
  }
}

// ---------------------------------------------------------------------------
// K3: k GroupNorm-apply + softmax over n.
// ---------------------------------------------------------------------------
__global__ __launch_bounds__(256) void k_softmax(const float* __restrict__ proj,
    const float* __restrict__ meanp, const float* __restrict__ rstdp,
    const float* __restrict__ gkg, const float* __restrict__ gkb,
    float* __restrict__ ksm) {
  const int bk = blockIdx.x;
  const int b = bk >> 4, kk = bk & 15;
  const int g = 16 + (kk >> 2);
  const float mu = meanp[b * NG_ + g], rs = rstdp[b * NG_ + g];
  const float ga = gkg[kk], be = gkb[kk];
  const float* p = proj + ((size_t)b * OTOT_ + 64 + kk) * N_;
  float* o = ksm + ((size_t)b * KK_ + kk) * N_;

  float xn[16];
  float m = -1e30f;
  #pragma unroll
  for (int i = 0; i < 16; ++i) {
    float v = (p[threadIdx.x + i * 256] - mu) * rs * ga + be;
    xn[i] = v;
    m = fmaxf(m, v);
  }
  __shared__ float red[256];
  red[threadIdx.x] = m; __syncthreads();
  for (int off = 128; off > 0; off >>= 1) {
    if (threadIdx.x < off)
      red[threadIdx.x] = fmaxf(red[threadIdx.x], red[threadIdx.x + off]);
    __syncthreads();
  }
  m = red[0];
  __syncthreads();
  float s = 0.f;
  #pragma unroll
  for (int i = 0; i < 16; ++i) { xn[i] = __expf(xn[i] - m); s += xn[i]; }
  red[threadIdx.x] = s; __syncthreads();
  for (int off = 128; off > 0; off >>= 1) {
    if (threadIdx.x < off) red[threadIdx.x] += red[threadIdx.x + off];
    __syncthreads();
  }
  float inv = 1.f / red[0];
  #pragma unroll
  for (int i = 0; i < 16; ++i) o[threadIdx.x + i * 256] = xn[i] * inv;
}

// ---------------------------------------------------------------------------
// K4 v2: content lambda, float4 loads (4 positions/thread).
// lam[b,k,v] = sum_n ksm[b,k,n] * v_norm[b,v,n].
// ---------------------------------------------------------------------------
__global__ __launch_bounds__(256) void k_lam(const float* __restrict__ proj,
    const float* __restrict__ ksm,
    const float* __restrict__ meanp, const float* __restrict__ rstdp,
    const float* __restrict__ gvg, const float* __restrict__ gvb,
    float* __restrict__ lam) {
  const int bv = blockIdx.x;
  const int b = bv >> 6, v = bv & 63;
  const int g = 20 + (v >> 2);
  const float mu = meanp[b * NG_ + g], rs = rstdp[b * NG_ + g];
  const float ga = gvg[v], be = gvb[v];
  const float* pv = proj + ((size_t)b * OTOT_ + 80 + v) * N_;
  const float* pk = ksm + (size_t)b * KK_ * N_;

  float acc[16];
  #pragma unroll
  for (int k = 0; k < 16; ++k) acc[k] = 0.f;
  for (int n = threadIdx.x * 4; n < N_; n += 1024) {
    float4 vn = *reinterpret_cast<const float4*>(pv + n);
    vn.x = (vn.x - mu) * rs * ga + be;
    vn.y = (vn.y - mu) * rs * ga + be;
    vn.z = (vn.z - mu) * rs * ga + be;
    vn.w = (vn.w - mu) * rs * ga + be;
    #pragma unroll
    for (int k = 0; k < 16; ++k) {
      const float4 kv = *reinterpret_cast<const float4*>(pk + (size_t)k * N_ + n);
      acc[k] += kv.x * vn.x + kv.y * vn.y + kv.z * vn.z + kv.w * vn.w;
    }
  }
  __shared__ float red[64];
  const int lane = threadIdx.x & 63, wid = threadIdx.x >> 6;
  #pragma unroll
  for (int k = 0; k < 16; ++k) {
    float s = acc[k];
    #pragma unroll
    for (int off = 32; off > 0; off >>= 1) s += __shfl_down(s, off, 64);
    if (lane == 0) red[wid * 16 + k] = s;
  }
  __syncthreads();
  if (threadIdx.x < 16) {
    float s = red[threadIdx.x] + red[16 + threadIdx.x] +
              red[32 + threadIdx.x] + red[48 + threadIdx.x];
    lam[((size_t)b * KK_ + threadIdx.x) * VV_ + v] = s;
  }
}

// ---------------------------------------------------------------------------
// K-QE: qe[t][n] = sum_k GN(q)[h,k,n]*emb[k,t] once per (b,h,n), bf16 out.
// ---------------------------------------------------------------------------
__global__ __launch_bounds__(256) void k_qe(const float* __restrict__ proj,
    const float* __restrict__ meanp, const float* __restrict__ rstdp,
    const float* __restrict__ gqg, const float* __restrict__ gqb,
    const float* __restrict__ emb, unsigned short* __restrict__ qeb) {
  const int strip = blockIdx.x;   // 16
  const int h     = blockIdx.y;   // 4
  const int b     = blockIdx.z;   // 16
  const int r0    = strip * 4;
  const int tid   = threadIdx.x;
  const int wid   = __builtin_amdgcn_readfirstlane(tid >> 6);  // tap-split
  const int slot  = tid & 63;
  const int ty    = slot >> 4, txg = slot & 15;
  const int x0    = txg << 2;
  const int n0    = (r0 + ty) * W_ + x0;

  const float* pb = proj + (size_t)b * OTOT_ * N_;

  float qn[4][16];
  #pragma unroll
  for (int k = 0; k < 16; ++k) {
    const int o = h * 16 + k, g = o >> 2;
    const float mu = meanp[b * NG_ + g], rs = rstdp[b * NG_ + g];
    const float ga = gqg[o], be = gqb[o];
    const float4 qv = *reinterpret_cast<const float4*>(pb + (size_t)o * N_ + n0);
    qn[0][k] = (qv.x - mu) * rs * ga + be;
    qn[1][k] = (qv.y - mu) * rs * ga + be;
    qn[2][k] = (qv.z - mu) * rs * ga + be;
    qn[3][k] = (qv.w - mu) * rs * ga + be;
  }

  unsigned short* qb = qeb + (size_t)(b * 4 + h) * 49 * N_;
  const int t0 = wid * 13;
  const int t1 = (t0 + 13 < 49) ? (t0 + 13) : 49;
  for (int t = t0; t < t1; ++t) {
    float p0 = 0.f, p1 = 0.f, p2 = 0.f, p3 = 0.f;
    #pragma unroll
    for (int k = 0; k < 16; ++k) {
      const float e = emb[k * 49 + t];   // uniform -> scalar
      p0 += qn[0][k] * e; p1 += qn[1][k] * e;
      p2 += qn[2][k] * e; p3 += qn[3][k] * e;
    }
    uint2 pk;
    pk.x = packbf(p0, p1);
    pk.y = packbf(p2, p3);
    *reinterpret_cast<uint2*>(&qb[(size_t)t * N_ + n0]) = pk;
  }
}

// ---------------------------------------------------------------------------
// K5 v7 (R11 proven): conv+combine, qe from global, one v-set per block,
// XCD swizzle, LDS only s_v.
// ---------------------------------------------------------------------------
__global__ __launch_bounds__(256) void k_final_v7(const float* __restrict__ proj,
    const float* __restrict__ meanp, const float* __restrict__ rstdp,
    const float* __restrict__ gqg, const float* __restrict__ gqb,
    const float* __restrict__ gvg, const float* __restrict__ gvb,
    const unsigned short* __restrict__ qeb, const float* __restrict__ lam,
    float* __restrict__ out) {
  const int wgid = (blockIdx.x & 7) * 512 + (blockIdx.x >> 3);
  const int b     = wgid >> 8;
  const int r2    = wgid & 255;
  const int h     = r2 & 3;
  const int strip = (r2 >> 2) & 15;
  const int s     = r2 >> 6;

  const int r0    = strip * 4;
  const int tid   = threadIdx.x;
  const int vlane = __builtin_amdgcn_readfirstlane(tid >> 6);
  const int slot  = tid & 63;
  const int ty    = slot >> 4;
  const int txg   = slot & 15;
  const int x0    = txg << 2;
  const int n0    = (r0 + ty) * W_ + x0;

  __shared__ unsigned short s_v[16 * 720];    // bf16 v[ch][10][72], 22.5 KB
  __shared__ float s_mu[NG_], s_rs[NG_];
  __shared__ float s_gvw[64], s_gvb[64];

  // phase 0: constants + zero the 2 pad columns of s_v
  if (tid < NG_) { s_mu[tid] = meanp[b * NG_ + tid]; s_rs[tid] = rstdp[b * NG_ + tid]; }
  else if (tid >= 64 && tid < 128) { s_gvw[tid - 64] = gvg[tid - 64]; s_gvb[tid - 64] = gvb[tid - 64]; }
  for (int i = tid; i < 320; i += 256) {
    const int vh = i / 20, rem = i % 20;
    const int ry = rem >> 1, side = rem & 1;
    uint2 z; z.x = 0u; z.y = 0u;
    *reinterpret_cast<uint2*>(&s_v[vh * 720 + ry * 72 + side * 68]) = z;
  }
  __syncthreads();

  const float* pb = proj + (size_t)b * OTOT_ * N_;

  // phase 1: stage this block's 16-ch v-set (division-free, 10 iters)
  {
    const int vh  = tid >> 4;          // 0..15
    const int rx4 = (tid & 15) + 1;    // 1..16
    const int gx0 = (rx4 << 2) - 4;
    const int v   = s * 16 + vh;
    const int g   = 20 + (v >> 2);
    const float mu = s_mu[g], rs = s_rs[g], ga = s_gvw[v], be = s_gvb[v];
    const float* src = pb + (size_t)(80 + v) * N_ + gx0;
    unsigned short* dst = &s_v[vh * 720 + (rx4 << 2)];
    #pragma unroll
    for (int ry = 0; ry < 10; ++ry) {
      const int gy = r0 - 3 + ry;      // block-uniform branch
      float4 f = make_float4(0.f, 0.f, 0.f, 0.f);
      if (gy >= 0 && gy < H_) {
        f = *reinterpret_cast<const float4*>(src + (size_t)gy * W_);
        f.x = (f.x - mu) * rs * ga + be;
        f.y = (f.y - mu) * rs * ga + be;
        f.z = (f.z - mu) * rs * ga + be;
        f.w = (f.w - mu) * rs * ga + be;
      }
      uint2 w;
      w.x = packbf(f.x, f.y);
      w.y = packbf(f.z, f.w);
      *reinterpret_cast<uint2*>(dst + ry * 72) = w;
    }
  }
  __syncthreads();

  // phase 2: content (k-outer, GN on the fly) + conv (qe from global)
  float acc[4][4];
  #pragma unroll
  for (int vj = 0; vj < 4; ++vj)
    #pragma unroll
    for (int p = 0; p < 4; ++p) acc[vj][p] = 0.f;

  const float* lb = lam + (size_t)b * 1024;
  #pragma unroll
  for (int k = 0; k < 16; ++k) {
    const int o = h * 16 + k, g = o >> 2;
    const float mu = s_mu[g], rs = s_rs[g];
    const float ga = gqg[o], be = gqb[o];   // uniform -> scalar
    const float4 qv = *reinterpret_cast<const float4*>(pb + (size_t)o * N_ + n0);
    const float q0 = (qv.x - mu) * rs * ga + be;
    const float q1 = (qv.y - mu) * rs * ga + be;
    const float q2 = (qv.z - mu) * rs * ga + be;
    const float q3 = (qv.w - mu) * rs * ga + be;
    #pragma unroll
    for (int vj = 0; vj < 4; ++vj) {
      const int v = __builtin_amdgcn_readfirstlane(s * 16 + vj * 4 + vlane);
      const float lv = lb[k * 64 + v];      // uniform -> scalar
      acc[vj][0] += q0 * lv; acc[vj][1] += q1 * lv;
      acc[vj][2] += q2 * lv; acc[vj][3] += q3 * lv;
    }
  }

  const unsigned short* qb = qeb + (size_t)(b * 4 + h) * 49 * N_ + n0;
  #pragma unroll
  for (int i = 0; i < 7; ++i) {
    float qeu[7][4];
    #pragma unroll
    for (int j = 0; j < 7; ++j) {
      const uint2 pk = *reinterpret_cast<const uint2*>(&qb[(size_t)(i * 7 + j) * N_]);
      qeu[j][0] = bflo(pk.x); qeu[j][1] = bfhi(pk.x);
      qeu[j][2] = bflo(pk.y); qeu[j][3] = bfhi(pk.y);
    }
    #pragma unroll
    for (int vj = 0; vj < 4; ++vj) {
      const int vh = vj * 4 + vlane;
      const unsigned short* sv = &s_v[vh * 720 + (ty + i) * 72 + x0];
      const uint2 wa = *reinterpret_cast<const uint2*>(sv);
      const uint2 wb = *reinterpret_cast<const uint2*>(sv + 4);
      const uint2 wc = *reinterpret_cast<const uint2*>(sv + 8);
      float wv[12];
      wv[0] = bflo(wa.x); wv[1] = bfhi(wa.x); wv[2]  = bflo(wa.y); wv[3]  = bfhi(wa.y);
      wv[4] = bflo(wb.x); wv[5] = bfhi(wb.x); wv[6]  = bflo(wb.y); wv[7]  = bfhi(wb.y);
      wv[8] = bflo(wc.x); wv[9] = bfhi(wc.x); wv[10] = bflo(wc.y); wv[11] = bfhi(wc.y);
      #pragma unroll
      for (int j = 0; j < 7; ++j)
        #pragma unroll
        for (int p = 0; p < 4; ++p)
          acc[vj][p] += qeu[j][p] * wv[p + j + 1];
    }
  }

  #pragma unroll
  for (int vj = 0; vj < 4; ++vj) {
    const int v = s * 16 + vj * 4 + vlane;
    float4 o4 = make_float4(acc[vj][0], acc[vj][1], acc[vj][2], acc[vj][3]);
    *reinterpret_cast<float4*>(out + ((size_t)b * 256 + h * 64 + v) * N_ + n0) = o4;
  }
}

// ---------------------------------------------------------------------------
extern "C" void kernel_launch(void* const* d_in, const int* in_sizes, int n_in,
                              void* d_out, int out_size, void* d_ws, size_t ws_size,
                              hipStream_t stream) {
  const float* x   = (const float*)d_in[0];
  const float* wq  = (const float*)d_in[1];
  const float* gqg = (const float*)d_in[2];
  const float* gqb = (const float*)d_in[3];
  const float* wk  = (const float*)d_in[4];
  const float* gkg = (const float*)d_in[5];
  const float* gkb = (const float*)d_in[6];
  const float* wv  = (const float*)d_in[7];
  const float* gvg = (const float*)d_in[8];
  const float* gvb = (const float*)d_in[9];
  const float* emb = (const float*)d_in[10];
  float* out = (float*)d_out;
  float* ws  = (float*)d_ws;

  float* proj  = ws;                                    // B*144*N floats
  float* meanp = proj + (size_t)B_ * OTOT_ * N_;        // B*36
  float* rstdp = meanp + B_ * NG_;                      // B*36
  float* ksm   = rstdp + B_ * NG_;                      // B*16*N
  float* lam   = ksm + (size_t)B_ * KK_ * N_;           // B*16*64
  unsigned short* qeb = (unsigned short*)(lam + (size_t)B_ * KK_ * VV_);

  k_proj<<<dim3(4, 18, B_), 256, 0, stream>>>(x, wq, wk, wv, proj);
  k_stats<<<dim3(B_ * NG_), 256, 0, stream>>>(proj, meanp, rstdp);
  k_softmax<<<dim3(B_ * KK_), 256, 0, stream>>>(proj, meanp, rstdp, gkg, gkb, ksm);
  k_lam<<<dim3(B_ * VV_), 256, 0, stream>>>(proj, ksm, meanp, rstdp, gvg, gvb, lam);
  k_qe<<<dim3(16, HEADS_, B_), 256, 0, stream>>>(proj, meanp, rstdp, gqg, gqb, emb, qeb);
  k_final_v7<<<dim3(4096), 256, 0, stream>>>(proj, meanp, rstdp,
      gqg, gqb, gvg, gvb, qeb, lam, out);
}

// Round 13
// 214.962 us; speedup vs baseline: 4.4351x; 1.0239x over previous
//
#include <hip/hip_runtime.h>
#include <math.h>

#define B_    16
#define C_    256
#define H_    64
#define W_    64
#define N_    4096
#define HEADS_ 4
#define KK_   16
#define VV_   64
#define M_    7
#define PAD_  3
#define OTOT_ 144   // 64 q + 16 k + 64 v channels
#define NG_   36    // 36 groups of 4 channels
#define EPS_  1e-5f

// bf16 helpers (round-half-up; error ~2^-9 relative, fine vs threshold)
__device__ inline unsigned packbf(float a, float b) {
  unsigned ua = __float_as_uint(a) + 0x8000u;
  unsigned ub = __float_as_uint(b) + 0x8000u;
  return (ua >> 16) | (ub & 0xffff0000u);
}
__device__ inline float bflo(unsigned u) { return __uint_as_float(u << 16); }
__device__ inline float bfhi(unsigned u) { return __uint_as_float(u & 0xffff0000u); }

// ---------------------------------------------------------------------------
// K1 v4: projection GEMM. o-tile 16 (proven), n-tile 512 (2 px/thread) ->
// 1152 blocks for occupancy at unchanged per-CU x cache traffic.
// ---------------------------------------------------------------------------
__global__ __launch_bounds__(256) void k_proj(const float* __restrict__ x,
    const float* __restrict__ wq, const float* __restrict__ wk,
    const float* __restrict__ wv, float* __restrict__ proj) {
  __shared__ float sw[16][256];
  const int tid = threadIdx.x;
  const int o0  = blockIdx.y * 16;
  const int b   = blockIdx.z;
  const int n0  = blockIdx.x * 512 + tid;

  for (int r = 0; r < 16; ++r) {
    int o = o0 + r;
    const float* wrow = (o < 64) ? (wq + o * C_)
                       : ((o < 80) ? (wk + (o - 64) * C_) : (wv + (o - 80) * C_));
    sw[r][tid] = wrow[tid];  // blockDim == C_ == 256
  }
  __syncthreads();

  float acc[16][2];
  #pragma unroll
  for (int r = 0; r < 16; ++r)
    #pragma unroll
    for (int p = 0; p < 2; ++p) acc[r][p] = 0.f;

  const float* xb = x + (size_t)b * C_ * N_;
  for (int c0 = 0; c0 < C_; c0 += 4) {
    float xv[4][2];
    #pragma unroll
    for (int i = 0; i < 4; ++i)
      #pragma unroll
      for (int p = 0; p < 2; ++p)
        xv[i][p] = xb[(size_t)(c0 + i) * N_ + n0 + p * 256];
    #pragma unroll
    for (int i = 0; i < 4; ++i) {
      #pragma unroll
      for (int r = 0; r < 16; ++r) {
        float w = sw[r][c0 + i];
        #pragma unroll
        for (int p = 0; p < 2; ++p) acc[r][p] += w * xv[i][p];
      }
    }
  }

  float* pb = proj + ((size_t)b * OTOT_ + o0) * N_ + n0;
  #pragma unroll
  for (int r = 0; r < 16; ++r)
    #pragma unroll
    for (int p = 0; p < 2; ++p)
      pb[(size_t)r * N_ + p * 256] = acc[r][p];
}

// ---------------------------------------------------------------------------
// K2 v3: GroupNorm stats, float4 loads.
// ---------------------------------------------------------------------------
__global__ __launch_bounds__(256) void k_stats(const float* __restrict__ proj,
    float* __restrict__ meanp, float* __restrict__ rstdp) {
  const int bg = blockIdx.x;           // b*36 + g
  const int b = bg / NG_, g = bg % NG_;
  const float* p = proj + ((size_t)b * OTOT_ + g * 4) * N_;
  float s = 0.f, s2 = 0.f;
  for (int i = threadIdx.x * 4; i < 4 * N_; i += 1024) {
    const float4 v = *reinterpret_cast<const float4*>(p + i);
    s  += v.x + v.y + v.z + v.w;
    s2 += v.x * v.x + v.y * v.y + v.z * v.z + v.w * v.w;
  }
  __shared__ float rs[256], rq[256];
  rs[threadIdx.x] = s; rq[threadIdx.x] = s2;
  __syncthreads();
  for (int off = 128; off > 0; off >>= 1) {
    if (threadIdx.x < off) {
      rs[threadIdx.x] += rs[threadIdx.x + off];
      rq[threadIdx.x] += rq[threadIdx.x + off];
    }
    __syncthreads();
  }
  if (threadIdx.x == 0) {
    float m   = rs[0] * (1.f / 16384.f);
    float var = rq[0] * (1.f / 16384.f) - m * m;
    meanp[bg] = m;
    rstdp[bg] = rsqrtf(var + EPS_);
  }
}

// ---------------------------------------------------------------------------
// K3: k GroupNorm-apply + softmax over n.
// ---------------------------------------------------------------------------
__global__ __launch_bounds__(256) void k_softmax(const float* __restrict__ proj,
    const float* __restrict__ meanp, const float* __restrict__ rstdp,
    const float* __restrict__ gkg, const float* __restrict__ gkb,
    float* __restrict__ ksm) {
  const int bk = blockIdx.x;
  const int b = bk >> 4, kk = bk & 15;
  const int g = 16 + (kk >> 2);
  const float mu = meanp[b * NG_ + g], rs = rstdp[b * NG_ + g];
  const float ga = gkg[kk], be = gkb[kk];
  const float* p = proj + ((size_t)b * OTOT_ + 64 + kk) * N_;
  float* o = ksm + ((size_t)b * KK_ + kk) * N_;

  float xn[16];
  float m = -1e30f;
  #pragma unroll
  for (int i = 0; i < 16; ++i) {
    float v = (p[threadIdx.x + i * 256] - mu) * rs * ga + be;
    xn[i] = v;
    m = fmaxf(m, v);
  }
  __shared__ float red[256];
  red[threadIdx.x] = m; __syncthreads();
  for (int off = 128; off > 0; off >>= 1) {
    if (threadIdx.x < off)
      red[threadIdx.x] = fmaxf(red[threadIdx.x], red[threadIdx.x + off]);
    __syncthreads();
  }
  m = red[0];
  __syncthreads();
  float s = 0.f;
  #pragma unroll
  for (int i = 0; i < 16; ++i) { xn[i] = __expf(xn[i] - m); s += xn[i]; }
  red[threadIdx.x] = s; __syncthreads();
  for (int off = 128; off > 0; off >>= 1) {
    if (threadIdx.x < off) red[threadIdx.x] += red[threadIdx.x + off];
    __syncthreads();
  }
  float inv = 1.f / red[0];
  #pragma unroll
  for (int i = 0; i < 16; ++i) o[threadIdx.x + i * 256] = xn[i] * inv;
}

// ---------------------------------------------------------------------------
// K4 v2: content lambda, float4 loads.
// ---------------------------------------------------------------------------
__global__ __launch_bounds__(256) void k_lam(const float* __restrict__ proj,
    const float* __restrict__ ksm,
    const float* __restrict__ meanp, const float* __restrict__ rstdp,
    const float* __restrict__ gvg, const float* __restrict__ gvb,
    float* __restrict__ lam) {
  const int bv = blockIdx.x;
  const int b = bv >> 6, v = bv & 63;
  const int g = 20 + (v >> 2);
  const float mu = meanp[b * NG_ + g], rs = rstdp[b * NG_ + g];
  const float ga = gvg[v], be = gvb[v];
  const float* pv = proj + ((size_t)b * OTOT_ + 80 + v) * N_;
  const float* pk = ksm + (size_t)b * KK_ * N_;

  float acc[16];
  #pragma unroll
  for (int k = 0; k < 16; ++k) acc[k] = 0.f;
  for (int n = threadIdx.x * 4; n < N_; n += 1024) {
    float4 vn = *reinterpret_cast<const float4*>(pv + n);
    vn.x = (vn.x - mu) * rs * ga + be;
    vn.y = (vn.y - mu) * rs * ga + be;
    vn.z = (vn.z - mu) * rs * ga + be;
    vn.w = (vn.w - mu) * rs * ga + be;
    #pragma unroll
    for (int k = 0; k < 16; ++k) {
      const float4 kv = *reinterpret_cast<const float4*>(pk + (size_t)k * N_ + n);
      acc[k] += kv.x * vn.x + kv.y * vn.y + kv.z * vn.z + kv.w * vn.w;
    }
  }
  __shared__ float red[64];
  const int lane = threadIdx.x & 63, wid = threadIdx.x >> 6;
  #pragma unroll
  for (int k = 0; k < 16; ++k) {
    float s = acc[k];
    #pragma unroll
    for (int off = 32; off > 0; off >>= 1) s += __shfl_down(s, off, 64);
    if (lane == 0) red[wid * 16 + k] = s;
  }
  __syncthreads();
  if (threadIdx.x < 16) {
    float s = red[threadIdx.x] + red[16 + threadIdx.x] +
              red[32 + threadIdx.x] + red[48 + threadIdx.x];
    lam[((size_t)b * KK_ + threadIdx.x) * VV_ + v] = s;
  }
}

// ---------------------------------------------------------------------------
// K-QE: qe[t][n] = sum_k GN(q)[h,k,n]*emb[k,t] once per (b,h,n), bf16 out.
// ---------------------------------------------------------------------------
__global__ __launch_bounds__(256) void k_qe(const float* __restrict__ proj,
    const float* __restrict__ meanp, const float* __restrict__ rstdp,
    const float* __restrict__ gqg, const float* __restrict__ gqb,
    const float* __restrict__ emb, unsigned short* __restrict__ qeb) {
  const int strip = blockIdx.x;   // 16
  const int h     = blockIdx.y;   // 4
  const int b     = blockIdx.z;   // 16
  const int r0    = strip * 4;
  const int tid   = threadIdx.x;
  const int wid   = __builtin_amdgcn_readfirstlane(tid >> 6);  // tap-split
  const int slot  = tid & 63;
  const int ty    = slot >> 4, txg = slot & 15;
  const int x0    = txg << 2;
  const int n0    = (r0 + ty) * W_ + x0;

  const float* pb = proj + (size_t)b * OTOT_ * N_;

  float qn[4][16];
  #pragma unroll
  for (int k = 0; k < 16; ++k) {
    const int o = h * 16 + k, g = o >> 2;
    const float mu = meanp[b * NG_ + g], rs = rstdp[b * NG_ + g];
    const float ga = gqg[o], be = gqb[o];
    const float4 qv = *reinterpret_cast<const float4*>(pb + (size_t)o * N_ + n0);
    qn[0][k] = (qv.x - mu) * rs * ga + be;
    qn[1][k] = (qv.y - mu) * rs * ga + be;
    qn[2][k] = (qv.z - mu) * rs * ga + be;
    qn[3][k] = (qv.w - mu) * rs * ga + be;
  }

  unsigned short* qb = qeb + (size_t)(b * 4 + h) * 49 * N_;
  const int t0 = wid * 13;
  const int t1 = (t0 + 13 < 49) ? (t0 + 13) : 49;
  for (int t = t0; t < t1; ++t) {
    float p0 = 0.f, p1 = 0.f, p2 = 0.f, p3 = 0.f;
    #pragma unroll
    for (int k = 0; k < 16; ++k) {
      const float e = emb[k * 49 + t];   // uniform -> scalar
      p0 += qn[0][k] * e; p1 += qn[1][k] * e;
      p2 += qn[2][k] * e; p3 += qn[3][k] * e;
    }
    uint2 pk;
    pk.x = packbf(p0, p1);
    pk.y = packbf(p2, p3);
    *reinterpret_cast<uint2*>(&qb[(size_t)t * N_ + n0]) = pk;
  }
}

// ---------------------------------------------------------------------------
// K5 v8: conv+combine; qe bulk-prefetched global->LDS (coalesced dwordx4),
// conv inner loop reads qe via ds_read_b64. One v-set per block, XCD
// swizzle, single hot barrier. LDS 47.5KB -> 3 blocks/CU.
// ---------------------------------------------------------------------------
__global__ __launch_bounds__(256) void k_final_v8(const float* __restrict__ proj,
    const float* __restrict__ meanp, const float* __restrict__ rstdp,
    const float* __restrict__ gqg, const float* __restrict__ gqb,
    const float* __restrict__ gvg, const float* __restrict__ gvb,
    const unsigned short* __restrict__ qeb, const float* __restrict__ lam,
    float* __restrict__ out) {
  const int wgid = (blockIdx.x & 7) * 512 + (blockIdx.x >> 3);
  const int b     = wgid >> 8;
  const int r2    = wgid & 255;
  const int h     = r2 & 3;
  const int strip = (r2 >> 2) & 15;
  const int s     = r2 >> 6;

  const int r0    = strip * 4;
  const int tid   = threadIdx.x;
  const int vlane = __builtin_amdgcn_readfirstlane(tid >> 6);
  const int slot  = tid & 63;
  const int ty    = slot >> 4;
  const int txg   = slot & 15;
  const int x0    = txg << 2;
  const int n0    = (r0 + ty) * W_ + x0;
  const int pos4  = ty * 64 + x0;

  __shared__ unsigned short s_qe[49 * 256];   // bf16 qe[t][pos], 24.5 KB
  __shared__ unsigned short s_v[16 * 720];    // bf16 v[ch][10][72], 22.5 KB
  __shared__ float s_mu[NG_], s_rs[NG_];
  __shared__ float s_gvw[64], s_gvb[64];

  // phase 0: constants + zero the 2 pad columns of s_v
  if (tid < NG_) { s_mu[tid] = meanp[b * NG_ + tid]; s_rs[tid] = rstdp[b * NG_ + tid]; }
  else if (tid >= 64 && tid < 128) { s_gvw[tid - 64] = gvg[tid - 64]; s_gvb[tid - 64] = gvb[tid - 64]; }
  for (int i = tid; i < 320; i += 256) {
    const int vh = i / 20, rem = i % 20;
    const int ry = rem >> 1, side = rem & 1;
    uint2 z; z.x = 0u; z.y = 0u;
    *reinterpret_cast<uint2*>(&s_v[vh * 720 + ry * 72 + side * 68]) = z;
  }
  __syncthreads();

  const float* pb = proj + (size_t)b * OTOT_ * N_;

  // phase 1a: bulk-prefetch qe tile (49 taps x 256 px, contiguous per tap)
  // into s_qe. 1568 dwordx4 chunks, coalesced.
  {
    const unsigned short* qb = qeb + (size_t)(b * 4 + h) * 49 * N_ + r0 * 64;
    for (int i = tid; i < 1568; i += 256) {
      const int t = i >> 5;          // tap
      const int r = i & 31;          // 16B chunk within the 512B tap row
      const uint4 d = *reinterpret_cast<const uint4*>(&qb[(size_t)t * N_ + r * 8]);
      *reinterpret_cast<uint4*>(&s_qe[t * 256 + r * 8]) = d;
    }
  }

  // phase 1b: stage this block's 16-ch v-set (division-free, 10 iters)
  {
    const int vh  = tid >> 4;          // 0..15
    const int rx4 = (tid & 15) + 1;    // 1..16
    const int gx0 = (rx4 << 2) - 4;
    const int v   = s * 16 + vh;
    const int g   = 20 + (v >> 2);
    const float mu = s_mu[g], rs = s_rs[g], ga = s_gvw[v], be = s_gvb[v];
    const float* src = pb + (size_t)(80 + v) * N_ + gx0;
    unsigned short* dst = &s_v[vh * 720 + (rx4 << 2)];
    #pragma unroll
    for (int ry = 0; ry < 10; ++ry) {
      const int gy = r0 - 3 + ry;      // block-uniform branch
      float4 f = make_float4(0.f, 0.f, 0.f, 0.f);
      if (gy >= 0 && gy < H_) {
        f = *reinterpret_cast<const float4*>(src + (size_t)gy * W_);
        f.x = (f.x - mu) * rs * ga + be;
        f.y = (f.y - mu) * rs * ga + be;
        f.z = (f.z - mu) * rs * ga + be;
        f.w = (f.w - mu) * rs * ga + be;
      }
      uint2 w;
      w.x = packbf(f.x, f.y);
      w.y = packbf(f.z, f.w);
      *reinterpret_cast<uint2*>(dst + ry * 72) = w;
    }
  }
  __syncthreads();   // the one hot barrier

  // phase 2: content (k-outer, GN on the fly, scalar lam) + conv (all-LDS)
  float acc[4][4];
  #pragma unroll
  for (int vj = 0; vj < 4; ++vj)
    #pragma unroll
    for (int p = 0; p < 4; ++p) acc[vj][p] = 0.f;

  const float* lb = lam + (size_t)b * 1024;
  #pragma unroll
  for (int k = 0; k < 16; ++k) {
    const int o = h * 16 + k, g = o >> 2;
    const float mu = s_mu[g], rs = s_rs[g];
    const float ga = gqg[o], be = gqb[o];   // uniform -> scalar
    const float4 qv = *reinterpret_cast<const float4*>(pb + (size_t)o * N_ + n0);
    const float q0 = (qv.x - mu) * rs * ga + be;
    const float q1 = (qv.y - mu) * rs * ga + be;
    const float q2 = (qv.z - mu) * rs * ga + be;
    const float q3 = (qv.w - mu) * rs * ga + be;
    #pragma unroll
    for (int vj = 0; vj < 4; ++vj) {
      const int v = __builtin_amdgcn_readfirstlane(s * 16 + vj * 4 + vlane);
      const float lv = lb[k * 64 + v];      // uniform -> scalar
      acc[vj][0] += q0 * lv; acc[vj][1] += q1 * lv;
      acc[vj][2] += q2 * lv; acc[vj][3] += q3 * lv;
    }
  }

  #pragma unroll
  for (int i = 0; i < 7; ++i) {
    float qeu[7][4];
    #pragma unroll
    for (int j = 0; j < 7; ++j) {
      const uint2 pk = *reinterpret_cast<const uint2*>(&s_qe[(i * 7 + j) * 256 + pos4]);
      qeu[j][0] = bflo(pk.x); qeu[j][1] = bfhi(pk.x);
      qeu[j][2] = bflo(pk.y); qeu[j][3] = bfhi(pk.y);
    }
    #pragma unroll
    for (int vj = 0; vj < 4; ++vj) {
      const int vh = vj * 4 + vlane;
      const unsigned short* sv = &s_v[vh * 720 + (ty + i) * 72 + x0];
      const uint2 wa = *reinterpret_cast<const uint2*>(sv);
      const uint2 wb = *reinterpret_cast<const uint2*>(sv + 4);
      const uint2 wc = *reinterpret_cast<const uint2*>(sv + 8);
      float wv[12];
      wv[0] = bflo(wa.x); wv[1] = bfhi(wa.x); wv[2]  = bflo(wa.y); wv[3]  = bfhi(wa.y);
      wv[4] = bflo(wb.x); wv[5] = bfhi(wb.x); wv[6]  = bflo(wb.y); wv[7]  = bfhi(wb.y);
      wv[8] = bflo(wc.x); wv[9] = bfhi(wc.x); wv[10] = bflo(wc.y); wv[11] = bfhi(wc.y);
      #pragma unroll
      for (int j = 0; j < 7; ++j)
        #pragma unroll
        for (int p = 0; p < 4; ++p)
          acc[vj][p] += qeu[j][p] * wv[p + j + 1];
    }
  }

  #pragma unroll
  for (int vj = 0; vj < 4; ++vj) {
    const int v = s * 16 + vj * 4 + vlane;
    float4 o4 = make_float4(acc[vj][0], acc[vj][1], acc[vj][2], acc[vj][3]);
    *reinterpret_cast<float4*>(out + ((size_t)b * 256 + h * 64 + v) * N_ + n0) = o4;
  }
}

// ---------------------------------------------------------------------------
extern "C" void kernel_launch(void* const* d_in, const int* in_sizes, int n_in,
                              void* d_out, int out_size, void* d_ws, size_t ws_size,
                              hipStream_t stream) {
  const float* x   = (const float*)d_in[0];
  const float* wq  = (const float*)d_in[1];
  const float* gqg = (const float*)d_in[2];
  const float* gqb = (const float*)d_in[3];
  const float* wk  = (const float*)d_in[4];
  const float* gkg = (const float*)d_in[5];
  const float* gkb = (const float*)d_in[6];
  const float* wv  = (const float*)d_in[7];
  const float* gvg = (const float*)d_in[8];
  const float* gvb = (const float*)d_in[9];
  const float* emb = (const float*)d_in[10];
  float* out = (float*)d_out;
  float* ws  = (float*)d_ws;

  float* proj  = ws;                                    // B*144*N floats
  float* meanp = proj + (size_t)B_ * OTOT_ * N_;        // B*36
  float* rstdp = meanp + B_ * NG_;                      // B*36
  float* ksm   = rstdp + B_ * NG_;                      // B*16*N
  float* lam   = ksm + (size_t)B_ * KK_ * N_;           // B*16*64
  unsigned short* qeb = (unsigned short*)(lam + (size_t)B_ * KK_ * VV_);

  k_proj<<<dim3(8, 9, B_), 256, 0, stream>>>(x, wq, wk, wv, proj);
  k_stats<<<dim3(B_ * NG_), 256, 0, stream>>>(proj, meanp, rstdp);
  k_softmax<<<dim3(B_ * KK_), 256, 0, stream>>>(proj, meanp, rstdp, gkg, gkb, ksm);
  k_lam<<<dim3(B_ * VV_), 256, 0, stream>>>(proj, ksm, meanp, rstdp, gvg, gvb, lam);
  k_qe<<<dim3(16, HEADS_, B_), 256, 0, stream>>>(proj, meanp, rstdp, gqg, gqb, emb, qeb);
  k_final_v8<<<dim3(4096), 256, 0, stream>>>(proj, meanp, rstdp,
      gqg, gqb, gvg, gvb, qeb, lam, out);
}

// Round 14
// 209.301 us; speedup vs baseline: 4.5551x; 1.0270x over previous
//
#include <hip/hip_runtime.h>
#include <math.h>

#define B_    16
#define C_    256
#define H_    64
#define W_    64
#define N_    4096
#define HEADS_ 4
#define KK_   16
#define VV_   64
#define M_    7
#define PAD_  3
#define OTOT_ 144   // 64 q + 16 k + 64 v channels
#define NG_   36    // 36 groups of 4 channels
#define EPS_  1e-5f

// bf16 helpers (round-half-up; error ~2^-9 relative, fine vs threshold)
__device__ inline unsigned packbf(float a, float b) {
  unsigned ua = __float_as_uint(a) + 0x8000u;
  unsigned ub = __float_as_uint(b) + 0x8000u;
  return (ua >> 16) | (ub & 0xffff0000u);
}
__device__ inline float bflo(unsigned u) { return __uint_as_float(u << 16); }
__device__ inline float bfhi(unsigned u) { return __uint_as_float(u & 0xffff0000u); }

// ---------------------------------------------------------------------------
// K1 v5: proven R5 body (o-tile 16, n-tile 1024, 4 px/thread) + XCD-chunked
// swizzle. Grid 576 = 8 XCD-chunks x 72. Physical XCD c runs chunk c =
// 8 (n,b)-groups x 9 o-tiles, so the 9 blocks sharing one 1MB x-slice all
// sit on one XCD: slice pulled from L3 once, re-served from that XCD's L2.
// ---------------------------------------------------------------------------
__global__ __launch_bounds__(256) void k_proj(const float* __restrict__ x,
    const float* __restrict__ wq, const float* __restrict__ wk,
    const float* __restrict__ wv, float* __restrict__ proj) {
  // bijective chunk swizzle: physical XCD (blockIdx.x % 8) gets chunk c
  const int wg  = (blockIdx.x & 7) * 72 + (blockIdx.x >> 3);
  const int grp = wg / 9;          // (n,b) group, consecutive within chunk
  const int o_t = wg - grp * 9;    // o-tile 0..8
  const int b   = grp >> 2;
  const int n_t = grp & 3;

  __shared__ float sw[16][256];
  const int tid = threadIdx.x;
  const int o0  = o_t * 16;
  const int n0  = n_t * 1024 + tid;

  for (int r = 0; r < 16; ++r) {
    int o = o0 + r;
    const float* wrow = (o < 64) ? (wq + o * C_)
                       : ((o < 80) ? (wk + (o - 64) * C_) : (wv + (o - 80) * C_));
    sw[r][tid] = wrow[tid];  // blockDim == C_ == 256
  }
  __syncthreads();

  float acc[16][4];
  #pragma unroll
  for (int r = 0; r < 16; ++r)
    #pragma unroll
    for (int p = 0; p < 4; ++p) acc[r][p] = 0.f;

  const float* xb = x + (size_t)b * C_ * N_;
  for (int c0 = 0; c0 < C_; c0 += 4) {
    float xv[4][4];
    #pragma unroll
    for (int i = 0; i < 4; ++i)
      #pragma unroll
      for (int p = 0; p < 4; ++p)
        xv[i][p] = xb[(size_t)(c0 + i) * N_ + n0 + p * 256];
    #pragma unroll
    for (int i = 0; i < 4; ++i) {
      #pragma unroll
      for (int r = 0; r < 16; ++r) {
        float w = sw[r][c0 + i];
        #pragma unroll
        for (int p = 0; p < 4; ++p) acc[r][p] += w * xv[i][p];
      }
    }
  }

  float* pb = proj + ((size_t)b * OTOT_ + o0) * N_ + n0;
  #pragma unroll
  for (int r = 0; r < 16; ++r)
    #pragma unroll
    for (int p = 0; p < 4; ++p)
      pb[(size_t)r * N_ + p * 256] = acc[r][p];
}

// ---------------------------------------------------------------------------
// K2 v3: GroupNorm stats, float4 loads.
// ---------------------------------------------------------------------------
__global__ __launch_bounds__(256) void k_stats(const float* __restrict__ proj,
    float* __restrict__ meanp, float* __restrict__ rstdp) {
  const int bg = blockIdx.x;           // b*36 + g
  const int b = bg / NG_, g = bg % NG_;
  const float* p = proj + ((size_t)b * OTOT_ + g * 4) * N_;
  float s = 0.f, s2 = 0.f;
  for (int i = threadIdx.x * 4; i < 4 * N_; i += 1024) {
    const float4 v = *reinterpret_cast<const float4*>(p + i);
    s  += v.x + v.y + v.z + v.w;
    s2 += v.x * v.x + v.y * v.y + v.z * v.z + v.w * v.w;
  }
  __shared__ float rs[256], rq[256];
  rs[threadIdx.x] = s; rq[threadIdx.x] = s2;
  __syncthreads();
  for (int off = 128; off > 0; off >>= 1) {
    if (threadIdx.x < off) {
      rs[threadIdx.x] += rs[threadIdx.x + off];
      rq[threadIdx.x] += rq[threadIdx.x + off];
    }
    __syncthreads();
  }
  if (threadIdx.x == 0) {
    float m   = rs[0] * (1.f / 16384.f);
    float var = rq[0] * (1.f / 16384.f) - m * m;
    meanp[bg] = m;
    rstdp[bg] = rsqrtf(var + EPS_);
  }
}

// ---------------------------------------------------------------------------
// K3: k GroupNorm-apply + softmax over n.
// ---------------------------------------------------------------------------
__global__ __launch_bounds__(256) void k_softmax(const float* __restrict__ proj,
    const float* __restrict__ meanp, const float* __restrict__ rstdp,
    const float* __restrict__ gkg, const float* __restrict__ gkb,
    float* __restrict__ ksm) {
  const int bk = blockIdx.x;
  const int b = bk >> 4, kk = bk & 15;
  const int g = 16 + (kk >> 2);
  const float mu = meanp[b * NG_ + g], rs = rstdp[b * NG_ + g];
  const float ga = gkg[kk], be = gkb[kk];
  const float* p = proj + ((size_t)b * OTOT_ + 64 + kk) * N_;
  float* o = ksm + ((size_t)b * KK_ + kk) * N_;

  float xn[16];
  float m = -1e30f;
  #pragma unroll
  for (int i = 0; i < 16; ++i) {
    float v = (p[threadIdx.x + i * 256] - mu) * rs * ga + be;
    xn[i] = v;
    m = fmaxf(m, v);
  }
  __shared__ float red[256];
  red[threadIdx.x] = m; __syncthreads();
  for (int off = 128; off > 0; off >>= 1) {
    if (threadIdx.x < off)
      red[threadIdx.x] = fmaxf(red[threadIdx.x], red[threadIdx.x + off]);
    __syncthreads();
  }
  m = red[0];
  __syncthreads();
  float s = 0.f;
  #pragma unroll
  for (int i = 0; i < 16; ++i) { xn[i] = __expf(xn[i] - m); s += xn[i]; }
  red[threadIdx.x] = s; __syncthreads();
  for (int off = 128; off > 0; off >>= 1) {
    if (threadIdx.x < off) red[threadIdx.x] += red[threadIdx.x + off];
    __syncthreads();
  }
  float inv = 1.f / red[0];
  #pragma unroll
  for (int i = 0; i < 16; ++i) o[threadIdx.x + i * 256] = xn[i] * inv;
}

// ---------------------------------------------------------------------------
// K4 v2: content lambda, float4 loads.
// ---------------------------------------------------------------------------
__global__ __launch_bounds__(256) void k_lam(const float* __restrict__ proj,
    const float* __restrict__ ksm,
    const float* __restrict__ meanp, const float* __restrict__ rstdp,
    const float* __restrict__ gvg, const float* __restrict__ gvb,
    float* __restrict__ lam) {
  const int bv = blockIdx.x;
  const int b = bv >> 6, v = bv & 63;
  const int g = 20 + (v >> 2);
  const float mu = meanp[b * NG_ + g], rs = rstdp[b * NG_ + g];
  const float ga = gvg[v], be = gvb[v];
  const float* pv = proj + ((size_t)b * OTOT_ + 80 + v) * N_;
  const float* pk = ksm + (size_t)b * KK_ * N_;

  float acc[16];
  #pragma unroll
  for (int k = 0; k < 16; ++k) acc[k] = 0.f;
  for (int n = threadIdx.x * 4; n < N_; n += 1024) {
    float4 vn = *reinterpret_cast<const float4*>(pv + n);
    vn.x = (vn.x - mu) * rs * ga + be;
    vn.y = (vn.y - mu) * rs * ga + be;
    vn.z = (vn.z - mu) * rs * ga + be;
    vn.w = (vn.w - mu) * rs * ga + be;
    #pragma unroll
    for (int k = 0; k < 16; ++k) {
      const float4 kv = *reinterpret_cast<const float4*>(pk + (size_t)k * N_ + n);
      acc[k] += kv.x * vn.x + kv.y * vn.y + kv.z * vn.z + kv.w * vn.w;
    }
  }
  __shared__ float red[64];
  const int lane = threadIdx.x & 63, wid = threadIdx.x >> 6;
  #pragma unroll
  for (int k = 0; k < 16; ++k) {
    float s = acc[k];
    #pragma unroll
    for (int off = 32; off > 0; off >>= 1) s += __shfl_down(s, off, 64);
    if (lane == 0) red[wid * 16 + k] = s;
  }
  __syncthreads();
  if (threadIdx.x < 16) {
    float s = red[threadIdx.x] + red[16 + threadIdx.x] +
              red[32 + threadIdx.x] + red[48 + threadIdx.x];
    lam[((size_t)b * KK_ + threadIdx.x) * VV_ + v] = s;
  }
}

// ---------------------------------------------------------------------------
// K-QE: qe[t][n] = sum_k GN(q)[h,k,n]*emb[k,t] once per (b,h,n), bf16 out.
// ---------------------------------------------------------------------------
__global__ __launch_bounds__(256) void k_qe(const float* __restrict__ proj,
    const float* __restrict__ meanp, const float* __restrict__ rstdp,
    const float* __restrict__ gqg, const float* __restrict__ gqb,
    const float* __restrict__ emb, unsigned short* __restrict__ qeb) {
  const int strip = blockIdx.x;   // 16
  const int h     = blockIdx.y;   // 4
  const int b     = blockIdx.z;   // 16
  const int r0    = strip * 4;
  const int tid   = threadIdx.x;
  const int wid   = __builtin_amdgcn_readfirstlane(tid >> 6);  // tap-split
  const int slot  = tid & 63;
  const int ty    = slot >> 4, txg = slot & 15;
  const int x0    = txg << 2;
  const int n0    = (r0 + ty) * W_ + x0;

  const float* pb = proj + (size_t)b * OTOT_ * N_;

  float qn[4][16];
  #pragma unroll
  for (int k = 0; k < 16; ++k) {
    const int o = h * 16 + k, g = o >> 2;
    const float mu = meanp[b * NG_ + g], rs = rstdp[b * NG_ + g];
    const float ga = gqg[o], be = gqb[o];
    const float4 qv = *reinterpret_cast<const float4*>(pb + (size_t)o * N_ + n0);
    qn[0][k] = (qv.x - mu) * rs * ga + be;
    qn[1][k] = (qv.y - mu) * rs * ga + be;
    qn[2][k] = (qv.z - mu) * rs * ga + be;
    qn[3][k] = (qv.w - mu) * rs * ga + be;
  }

  unsigned short* qb = qeb + (size_t)(b * 4 + h) * 49 * N_;
  const int t0 = wid * 13;
  const int t1 = (t0 + 13 < 49) ? (t0 + 13) : 49;
  for (int t = t0; t < t1; ++t) {
    float p0 = 0.f, p1 = 0.f, p2 = 0.f, p3 = 0.f;
    #pragma unroll
    for (int k = 0; k < 16; ++k) {
      const float e = emb[k * 49 + t];   // uniform -> scalar
      p0 += qn[0][k] * e; p1 += qn[1][k] * e;
      p2 += qn[2][k] * e; p3 += qn[3][k] * e;
    }
    uint2 pk;
    pk.x = packbf(p0, p1);
    pk.y = packbf(p2, p3);
    *reinterpret_cast<uint2*>(&qb[(size_t)t * N_ + n0]) = pk;
  }
}

// ---------------------------------------------------------------------------
// K5 v8 (R13 proven): conv+combine; qe bulk-prefetched global->LDS,
// conv inner loop all-LDS. One v-set per block, XCD swizzle, 1 hot barrier.
// ---------------------------------------------------------------------------
__global__ __launch_bounds__(256) void k_final_v8(const float* __restrict__ proj,
    const float* __restrict__ meanp, const float* __restrict__ rstdp,
    const float* __restrict__ gqg, const float* __restrict__ gqb,
    const float* __restrict__ gvg, const float* __restrict__ gvb,
    const unsigned short* __restrict__ qeb, const float* __restrict__ lam,
    float* __restrict__ out) {
  const int wgid = (blockIdx.x & 7) * 512 + (blockIdx.x >> 3);
  const int b     = wgid >> 8;
  const int r2    = wgid & 255;
  const int h     = r2 & 3;
  const int strip = (r2 >> 2) & 15;
  const int s     = r2 >> 6;

  const int r0    = strip * 4;
  const int tid   = threadIdx.x;
  const int vlane = __builtin_amdgcn_readfirstlane(tid >> 6);
  const int slot  = tid & 63;
  const int ty    = slot >> 4;
  const int txg   = slot & 15;
  const int x0    = txg << 2;
  const int n0    = (r0 + ty) * W_ + x0;
  const int pos4  = ty * 64 + x0;

  __shared__ unsigned short s_qe[49 * 256];   // bf16 qe[t][pos], 24.5 KB
  __shared__ unsigned short s_v[16 * 720];    // bf16 v[ch][10][72], 22.5 KB
  __shared__ float s_mu[NG_], s_rs[NG_];
  __shared__ float s_gvw[64], s_gvb[64];

  // phase 0: constants + zero the 2 pad columns of s_v
  if (tid < NG_) { s_mu[tid] = meanp[b * NG_ + tid]; s_rs[tid] = rstdp[b * NG_ + tid]; }
  else if (tid >= 64 && tid < 128) { s_gvw[tid - 64] = gvg[tid - 64]; s_gvb[tid - 64] = gvb[tid - 64]; }
  for (int i = tid; i < 320; i += 256) {
    const int vh = i / 20, rem = i % 20;
    const int ry = rem >> 1, side = rem & 1;
    uint2 z; z.x = 0u; z.y = 0u;
    *reinterpret_cast<uint2*>(&s_v[vh * 720 + ry * 72 + side * 68]) = z;
  }
  __syncthreads();

  const float* pb = proj + (size_t)b * OTOT_ * N_;

  // phase 1a: bulk-prefetch qe tile (49 taps x 256 px) into s_qe, coalesced.
  {
    const unsigned short* qb = qeb + (size_t)(b * 4 + h) * 49 * N_ + r0 * 64;
    for (int i = tid; i < 1568; i += 256) {
      const int t = i >> 5;          // tap
      const int r = i & 31;          // 16B chunk within the 512B tap row
      const uint4 d = *reinterpret_cast<const uint4*>(&qb[(size_t)t * N_ + r * 8]);
      *reinterpret_cast<uint4*>(&s_qe[t * 256 + r * 8]) = d;
    }
  }

  // phase 1b: stage this block's 16-ch v-set (division-free, 10 iters)
  {
    const int vh  = tid >> 4;          // 0..15
    const int rx4 = (tid & 15) + 1;    // 1..16
    const int gx0 = (rx4 << 2) - 4;
    const int v   = s * 16 + vh;
    const int g   = 20 + (v >> 2);
    const float mu = s_mu[g], rs = s_rs[g], ga = s_gvw[v], be = s_gvb[v];
    const float* src = pb + (size_t)(80 + v) * N_ + gx0;
    unsigned short* dst = &s_v[vh * 720 + (rx4 << 2)];
    #pragma unroll
    for (int ry = 0; ry < 10; ++ry) {
      const int gy = r0 - 3 + ry;      // block-uniform branch
      float4 f = make_float4(0.f, 0.f, 0.f, 0.f);
      if (gy >= 0 && gy < H_) {
        f = *reinterpret_cast<const float4*>(src + (size_t)gy * W_);
        f.x = (f.x - mu) * rs * ga + be;
        f.y = (f.y - mu) * rs * ga + be;
        f.z = (f.z - mu) * rs * ga + be;
        f.w = (f.w - mu) * rs * ga + be;
      }
      uint2 w;
      w.x = packbf(f.x, f.y);
      w.y = packbf(f.z, f.w);
      *reinterpret_cast<uint2*>(dst + ry * 72) = w;
    }
  }
  __syncthreads();   // the one hot barrier

  // phase 2: content (k-outer, GN on the fly, scalar lam) + conv (all-LDS)
  float acc[4][4];
  #pragma unroll
  for (int vj = 0; vj < 4; ++vj)
    #pragma unroll
    for (int p = 0; p < 4; ++p) acc[vj][p] = 0.f;

  const float* lb = lam + (size_t)b * 1024;
  #pragma unroll
  for (int k = 0; k < 16; ++k) {
    const int o = h * 16 + k, g = o >> 2;
    const float mu = s_mu[g], rs = s_rs[g];
    const float ga = gqg[o], be = gqb[o];   // uniform -> scalar
    const float4 qv = *reinterpret_cast<const float4*>(pb + (size_t)o * N_ + n0);
    const float q0 = (qv.x - mu) * rs * ga + be;
    const float q1 = (qv.y - mu) * rs * ga + be;
    const float q2 = (qv.z - mu) * rs * ga + be;
    const float q3 = (qv.w - mu) * rs * ga + be;
    #pragma unroll
    for (int vj = 0; vj < 4; ++vj) {
      const int v = __builtin_amdgcn_readfirstlane(s * 16 + vj * 4 + vlane);
      const float lv = lb[k * 64 + v];      // uniform -> scalar
      acc[vj][0] += q0 * lv; acc[vj][1] += q1 * lv;
      acc[vj][2] += q2 * lv; acc[vj][3] += q3 * lv;
    }
  }

  #pragma unroll
  for (int i = 0; i < 7; ++i) {
    float qeu[7][4];
    #pragma unroll
    for (int j = 0; j < 7; ++j) {
      const uint2 pk = *reinterpret_cast<const uint2*>(&s_qe[(i * 7 + j) * 256 + pos4]);
      qeu[j][0] = bflo(pk.x); qeu[j][1] = bfhi(pk.x);
      qeu[j][2] = bflo(pk.y); qeu[j][3] = bfhi(pk.y);
    }
    #pragma unroll
    for (int vj = 0; vj < 4; ++vj) {
      const int vh = vj * 4 + vlane;
      const unsigned short* sv = &s_v[vh * 720 + (ty + i) * 72 + x0];
      const uint2 wa = *reinterpret_cast<const uint2*>(sv);
      const uint2 wb = *reinterpret_cast<const uint2*>(sv + 4);
      const uint2 wc = *reinterpret_cast<const uint2*>(sv + 8);
      float wv[12];
      wv[0] = bflo(wa.x); wv[1] = bfhi(wa.x); wv[2]  = bflo(wa.y); wv[3]  = bfhi(wa.y);
      wv[4] = bflo(wb.x); wv[5] = bfhi(wb.x); wv[6]  = bflo(wb.y); wv[7]  = bfhi(wb.y);
      wv[8] = bflo(wc.x); wv[9] = bfhi(wc.x); wv[10] = bflo(wc.y); wv[11] = bfhi(wc.y);
      #pragma unroll
      for (int j = 0; j < 7; ++j)
        #pragma unroll
        for (int p = 0; p < 4; ++p)
          acc[vj][p] += qeu[j][p] * wv[p + j + 1];
    }
  }

  #pragma unroll
  for (int vj = 0; vj < 4; ++vj) {
    const int v = s * 16 + vj * 4 + vlane;
    float4 o4 = make_float4(acc[vj][0], acc[vj][1], acc[vj][2], acc[vj][3]);
    *reinterpret_cast<float4*>(out + ((size_t)b * 256 + h * 64 + v) * N_ + n0) = o4;
  }
}

// ---------------------------------------------------------------------------
extern "C" void kernel_launch(void* const* d_in, const int* in_sizes, int n_in,
                              void* d_out, int out_size, void* d_ws, size_t ws_size,
                              hipStream_t stream) {
  const float* x   = (const float*)d_in[0];
  const float* wq  = (const float*)d_in[1];
  const float* gqg = (const float*)d_in[2];
  const float* gqb = (const float*)d_in[3];
  const float* wk  = (const float*)d_in[4];
  const float* gkg = (const float*)d_in[5];
  const float* gkb = (const float*)d_in[6];
  const float* wv  = (const float*)d_in[7];
  const float* gvg = (const float*)d_in[8];
  const float* gvb = (const float*)d_in[9];
  const float* emb = (const float*)d_in[10];
  float* out = (float*)d_out;
  float* ws  = (float*)d_ws;

  float* proj  = ws;                                    // B*144*N floats
  float* meanp = proj + (size_t)B_ * OTOT_ * N_;        // B*36
  float* rstdp = meanp + B_ * NG_;                      // B*36
  float* ksm   = rstdp + B_ * NG_;                      // B*16*N
  float* lam   = ksm + (size_t)B_ * KK_ * N_;           // B*16*64
  unsigned short* qeb = (unsigned short*)(lam + (size_t)B_ * KK_ * VV_);

  k_proj<<<dim3(576), 256, 0, stream>>>(x, wq, wk, wv, proj);
  k_stats<<<dim3(B_ * NG_), 256, 0, stream>>>(proj, meanp, rstdp);
  k_softmax<<<dim3(B_ * KK_), 256, 0, stream>>>(proj, meanp, rstdp, gkg, gkb, ksm);
  k_lam<<<dim3(B_ * VV_), 256, 0, stream>>>(proj, ksm, meanp, rstdp, gvg, gvb, lam);
  k_qe<<<dim3(16, HEADS_, B_), 256, 0, stream>>>(proj, meanp, rstdp, gqg, gqb, emb, qeb);
  k_final_v8<<<dim3(4096), 256, 0, stream>>>(proj, meanp, rstdp,
      gqg, gqb, gvg, gvb, qeb, lam, out);
}